// Round 1
// baseline (764.129 us; speedup 1.0000x reference)
//
#include <hip/hip_runtime.h>
#include <cmath>

#define B_ 64
#define N_ 19
#define SEG_ 15
#define T_ 400
#define FIN_ 64
#define HID_ 128
#define K_ 4
#define NH_ 4
#define DM_ 64
#define FF_ 128
#define L_ 4
#define NC_ 3
#define EPS_ 1e-5f

// ---------------- Kernel 1: temporal encoder ----------------
// One block per (b,s,n) row. conv1(k25,s4,p12) -> relu -> maxpool4 fused
// (thread computes 4 conv outputs = 1 pooled output), conv2(k9,s2,p4) ->
// relu -> maxpool2 -> mean fused in epilogue.
__global__ __launch_bounds__(256) void k_temporal(
    const float* __restrict__ X, const float* __restrict__ c1w,
    const float* __restrict__ c1b, const float* __restrict__ c2w,
    const float* __restrict__ c2b, float* __restrict__ Xf) {
  const int row = blockIdx.x;            // (b*SEG+s)*N + n
  const int n = row % N_;
  const int s = (row / N_) % SEG_;
  const int b = row / (N_ * SEG_);
  const int tid = threadIdx.x;

  __shared__ float xp[424];       // padded input: xp[i] = x[i-12]
  __shared__ float w1s[800];      // conv1 weights [32][25]
  __shared__ float p1p[32][40];   // pooled conv1, padded: col j+4 holds p1[j], zeros elsewhere
  __shared__ float c2s[64][13];

  for (int i = tid; i < 800; i += 256) w1s[i] = c1w[i];
  for (int i = tid; i < 32 * 40; i += 256) ((float*)p1p)[i] = 0.f;

  const float* xin = X + (((size_t)b * N_ + n) * SEG_ + s) * T_;
  for (int i = tid; i < 421; i += 256) {
    int t = i - 12;
    xp[i] = (t >= 0 && t < T_) ? xin[t] : 0.f;
  }
  __syncthreads();

  // conv1 + relu + pool4 -> p1[32][25]; task = oc (fast, lane-contiguous) x j
  for (int task = tid; task < 800; task += 256) {
    const int oc = task & 31;
    const int j = task >> 5;
    float wr[25];
#pragma unroll
    for (int k = 0; k < 25; ++k) wr[k] = w1s[oc * 25 + k];
    float xr[37];   // input window for 4 conv outputs: indices 16j .. 16j+36
#pragma unroll
    for (int k = 0; k < 37; ++k) xr[k] = xp[16 * j + k];
    const float bias = c1b[oc];
    float m = -1e30f;
#pragma unroll
    for (int p = 0; p < 4; ++p) {
      float acc = bias;
#pragma unroll
      for (int k = 0; k < 25; ++k) acc += xr[4 * p + k] * wr[k];
      m = fmaxf(m, acc);
    }
    p1p[oc][j + 4] = fmaxf(m, 0.f);   // relu(max) == max(relu)
  }
  __syncthreads();

  // conv2: thread = (oc2 = tid>>2, g = tid&3) owns op in {4g..4g+3} (op<13)
  {
    const int oc2 = tid >> 2;
    const int g = tid & 3;
    const float bias = c2b[oc2];
    float acc[4] = {bias, bias, bias, bias};
    const float* wbase = c2w + oc2 * 32 * 9;
    for (int ic = 0; ic < 32; ++ic) {
      float wv[9];
#pragma unroll
      for (int k = 0; k < 9; ++k) wv[k] = wbase[ic * 9 + k];
      const float* pr = &p1p[ic][8 * g];   // padded idx 2*op+k = 8g + 2i + k
      float xr[15];
#pragma unroll
      for (int k = 0; k < 15; ++k) xr[k] = pr[k];  // max idx 8*3+14=38 < 40 (zeros)
#pragma unroll
      for (int i = 0; i < 4; ++i)
#pragma unroll
        for (int k = 0; k < 9; ++k) acc[i] += xr[2 * i + k] * wv[k];
    }
#pragma unroll
    for (int i = 0; i < 4; ++i) {
      int op = 4 * g + i;
      if (op < 13) c2s[oc2][op] = acc[i];
    }
  }
  __syncthreads();

  // relu + pool2 (drops op=12) + mean over 6
  if (tid < 64) {
    float ssum = 0.f;
#pragma unroll
    for (int j = 0; j < 6; ++j) {
      float v = fmaxf(c2s[tid][2 * j], c2s[tid][2 * j + 1]);
      ssum += fmaxf(v, 0.f);
    }
    Xf[(size_t)row * FIN_ + tid] = ssum * (1.f / 6.f);
  }
}

// ---------------- Kernel 2: GCN layer 1 ----------------
// Per (b,s): H1 = relu(BN( Abar @ (Xf @ W1^T) )), Abar = sum_k alpha_k A_k
__global__ __launch_bounds__(256) void k_gcn1(
    const float* __restrict__ A, const float* __restrict__ Xf,
    const float* __restrict__ W, const float* __restrict__ q,
    const float* __restrict__ bg, const float* __restrict__ bb,
    const float* __restrict__ bm, const float* __restrict__ bv,
    float* __restrict__ H1) {
  const int bs = blockIdx.x;
  const int b = bs / SEG_;
  const int s = bs % SEG_;
  const int tid = threadIdx.x;

  __shared__ float abar[N_ * N_];
  __shared__ float xs[N_ * FIN_];
  __shared__ float wsh[HID_ * 65];   // W1 [128][64] padded stride 65
  __shared__ float ybuf[N_ * HID_];
  __shared__ float scale[HID_], shift[HID_];

  float q0 = q[0], q1 = q[1], q2 = q[2], q3 = q[3];
  float mx = fmaxf(fmaxf(q0, q1), fmaxf(q2, q3));
  float e0 = expf(q0 - mx), e1 = expf(q1 - mx), e2 = expf(q2 - mx), e3 = expf(q3 - mx);
  float inv = 1.f / (e0 + e1 + e2 + e3);
  const float a0 = e0 * inv, a1 = e1 * inv, a2 = e2 * inv, a3 = e3 * inv;

  const size_t kstride = (size_t)SEG_ * N_ * N_;
  const float* Ab = A + ((size_t)b * K_ * SEG_ + s) * (N_ * N_);
  for (int i = tid; i < N_ * N_; i += 256)
    abar[i] = a0 * Ab[i] + a1 * Ab[i + kstride] + a2 * Ab[i + 2 * kstride] + a3 * Ab[i + 3 * kstride];

  const float* xb = Xf + (size_t)bs * N_ * FIN_;
  for (int i = tid; i < N_ * FIN_; i += 256) xs[i] = xb[i];

  for (int i = tid; i < HID_ * FIN_; i += 256) wsh[(i >> 6) * 65 + (i & 63)] = W[i];

  for (int o = tid; o < HID_; o += 256) {
    float sc = bg[o] * rsqrtf(bv[o] + EPS_);
    scale[o] = sc;
    shift[o] = bb[o] - bm[o] * sc;
  }
  __syncthreads();

  for (int idx = tid; idx < N_ * HID_; idx += 256) {
    int nn = idx >> 7, o = idx & 127;
    float acc = 0.f;
    const float* xr = &xs[nn * FIN_];
    const float* wr = &wsh[o * 65];
#pragma unroll 8
    for (int f = 0; f < FIN_; ++f) acc += xr[f] * wr[f];
    ybuf[idx] = acc;
  }
  __syncthreads();

  float* Ho = H1 + (size_t)bs * N_ * HID_;
  for (int idx = tid; idx < N_ * HID_; idx += 256) {
    int nn = idx >> 7, o = idx & 127;
    float acc = 0.f;
    const float* ar = &abar[nn * N_];
#pragma unroll
    for (int m = 0; m < N_; ++m) acc += ar[m] * ybuf[m * HID_ + o];
    Ho[idx] = fmaxf(acc * scale[o] + shift[o], 0.f);
  }
}

// ---------------- Kernel 3: GCN layer 2 + node mean ----------------
__global__ __launch_bounds__(256) void k_gcn2(
    const float* __restrict__ A, const float* __restrict__ H1,
    const float* __restrict__ W, const float* __restrict__ q,
    const float* __restrict__ bg, const float* __restrict__ bb,
    const float* __restrict__ bm, const float* __restrict__ bv,
    float* __restrict__ G) {
  const int bs = blockIdx.x;
  const int b = bs / SEG_;
  const int s = bs % SEG_;
  const int tid = threadIdx.x;

  __shared__ float abar[N_ * N_];
  __shared__ float hs[N_ * HID_];     // 2432
  __shared__ float wsh[FIN_ * 129];   // W2 [64][128] padded stride 129
  __shared__ float ybuf[N_ * FIN_];
  __shared__ float zbuf[N_ * FIN_];
  __shared__ float scale[FIN_], shift[FIN_];

  float q0 = q[0], q1 = q[1], q2 = q[2], q3 = q[3];
  float mx = fmaxf(fmaxf(q0, q1), fmaxf(q2, q3));
  float e0 = expf(q0 - mx), e1 = expf(q1 - mx), e2 = expf(q2 - mx), e3 = expf(q3 - mx);
  float inv = 1.f / (e0 + e1 + e2 + e3);
  const float a0 = e0 * inv, a1 = e1 * inv, a2 = e2 * inv, a3 = e3 * inv;

  const size_t kstride = (size_t)SEG_ * N_ * N_;
  const float* Ab = A + ((size_t)b * K_ * SEG_ + s) * (N_ * N_);
  for (int i = tid; i < N_ * N_; i += 256)
    abar[i] = a0 * Ab[i] + a1 * Ab[i + kstride] + a2 * Ab[i + 2 * kstride] + a3 * Ab[i + 3 * kstride];

  const float* hb = H1 + (size_t)bs * N_ * HID_;
  for (int i = tid; i < N_ * HID_; i += 256) hs[i] = hb[i];

  for (int i = tid; i < FIN_ * HID_; i += 256) wsh[(i >> 7) * 129 + (i & 127)] = W[i];

  for (int o = tid; o < FIN_; o += 256) {
    float sc = bg[o] * rsqrtf(bv[o] + EPS_);
    scale[o] = sc;
    shift[o] = bb[o] - bm[o] * sc;
  }
  __syncthreads();

  for (int idx = tid; idx < N_ * FIN_; idx += 256) {
    int nn = idx >> 6, o = idx & 63;
    float acc = 0.f;
    const float* hr = &hs[nn * HID_];
    const float* wr = &wsh[o * 129];
#pragma unroll 8
    for (int f = 0; f < HID_; ++f) acc += hr[f] * wr[f];
    ybuf[idx] = acc;
  }
  __syncthreads();

  for (int idx = tid; idx < N_ * FIN_; idx += 256) {
    int nn = idx >> 6, o = idx & 63;
    float acc = 0.f;
    const float* ar = &abar[nn * N_];
#pragma unroll
    for (int m = 0; m < N_; ++m) acc += ar[m] * ybuf[m * FIN_ + o];
    zbuf[idx] = fmaxf(acc * scale[o] + shift[o], 0.f);
  }
  __syncthreads();

  if (tid < FIN_) {
    float ssum = 0.f;
#pragma unroll
    for (int nn = 0; nn < N_; ++nn) ssum += zbuf[nn * FIN_ + tid];
    G[(size_t)bs * FIN_ + tid] = ssum * (1.f / (float)N_);
  }
}

// ---------------- Kernel 4: transformer (4 layers) + classifier ----------------
// One block per batch element; S=16 tokens, DM=64 state held in LDS.
__global__ __launch_bounds__(256) void k_transformer(
    const float* __restrict__ G, const float* __restrict__ cls,
    const float* __restrict__ pos,
    const float* __restrict__ wqkv, const float* __restrict__ bqkv,
    const float* __restrict__ wo, const float* __restrict__ bo,
    const float* __restrict__ ln1g, const float* __restrict__ ln1b,
    const float* __restrict__ w1, const float* __restrict__ b1,
    const float* __restrict__ w2, const float* __restrict__ b2,
    const float* __restrict__ ln2g, const float* __restrict__ ln2b,
    const float* __restrict__ clfw, const float* __restrict__ clfb,
    float* __restrict__ out) {
  const int b = blockIdx.x;
  const int tid = threadIdx.x;
  const int S = SEG_ + 1;  // 16

  __shared__ float xbuf[16 * 64];
  __shared__ float qkvb[16 * 193];   // stride 193: bank-conflict-free strided reads
  __shared__ float scb[NH_ * 16 * 16];
  __shared__ float obuf[16 * 64];
  __shared__ float h1b[16 * 128];
  __shared__ float tmpb[16 * 64];

  for (int i = tid; i < S * DM_; i += 256) {
    int t = i >> 6, d = i & 63;
    float base = (t == 0) ? cls[d] : G[((size_t)b * SEG_ + (t - 1)) * DM_ + d];
    xbuf[i] = base + pos[t * DM_ + d];
  }
  __syncthreads();

  for (int l = 0; l < L_; ++l) {
    const float* Wqkv = wqkv + (size_t)l * 3 * DM_ * DM_;
    const float* Bqkv = bqkv + l * 3 * DM_;
    const float* Wo = wo + (size_t)l * DM_ * DM_;
    const float* Bo = bo + l * DM_;
    const float* L1g = ln1g + l * DM_;
    const float* L1b = ln1b + l * DM_;
    const float* W1 = w1 + (size_t)l * FF_ * DM_;
    const float* B1 = b1 + l * FF_;
    const float* W2 = w2 + (size_t)l * DM_ * FF_;
    const float* B2 = b2 + l * DM_;
    const float* L2g = ln2g + l * DM_;
    const float* L2b = ln2b + l * DM_;

    // qkv = x @ Wqkv^T + b
    for (int idx = tid; idx < S * 192; idx += 256) {
      int t = idx / 192, j = idx % 192;
      float acc = Bqkv[j];
      const float* xr = &xbuf[t * 64];
      const float* wr = &Wqkv[j * 64];
#pragma unroll 8
      for (int d = 0; d < 64; ++d) acc += xr[d] * wr[d];
      qkvb[t * 193 + j] = acc;
    }
    __syncthreads();

    // scores = q @ k^T / sqrt(16)
    for (int idx = tid; idx < NH_ * 16 * 16; idx += 256) {
      int h = idx >> 8, t = (idx >> 4) & 15, u = idx & 15;
      const float* qr = &qkvb[t * 193 + h * 16];
      const float* kr = &qkvb[u * 193 + 64 + h * 16];
      float acc = 0.f;
#pragma unroll
      for (int d = 0; d < 16; ++d) acc += qr[d] * kr[d];
      scb[idx] = acc * 0.25f;
    }
    __syncthreads();

    // softmax rows (one per (h,t))
    if (tid < NH_ * 16) {
      float* r = &scb[tid * 16];
      float mxv = r[0];
#pragma unroll
      for (int u = 1; u < 16; ++u) mxv = fmaxf(mxv, r[u]);
      float sum = 0.f;
#pragma unroll
      for (int u = 0; u < 16; ++u) { float e = expf(r[u] - mxv); r[u] = e; sum += e; }
      float inv = 1.f / sum;
#pragma unroll
      for (int u = 0; u < 16; ++u) r[u] *= inv;
    }
    __syncthreads();

    // o = attn @ v
    for (int idx = tid; idx < S * DM_; idx += 256) {
      int t = idx >> 6, e = idx & 63;
      int h = e >> 4, d = e & 15;
      const float* pr = &scb[(h * 16 + t) * 16];
      float acc = 0.f;
#pragma unroll
      for (int u = 0; u < 16; ++u) acc += pr[u] * qkvb[u * 193 + 128 + h * 16 + d];
      obuf[idx] = acc;
    }
    __syncthreads();

    // proj + residual
    for (int idx = tid; idx < S * DM_; idx += 256) {
      int t = idx >> 6, d = idx & 63;
      float acc = Bo[d];
      const float* orow = &obuf[t * 64];
      const float* wr = &Wo[d * 64];
#pragma unroll 8
      for (int e = 0; e < 64; ++e) acc += orow[e] * wr[e];
      tmpb[idx] = xbuf[idx] + acc;
    }
    __syncthreads();

    // LN1
    if (tid < S) {
      const float* r = &tmpb[tid * 64];
      float mu = 0.f;
      for (int d = 0; d < 64; ++d) mu += r[d];
      mu *= (1.f / 64.f);
      float var = 0.f;
      for (int d = 0; d < 64; ++d) { float u = r[d] - mu; var += u * u; }
      var *= (1.f / 64.f);
      float rs = rsqrtf(var + EPS_);
      for (int d = 0; d < 64; ++d)
        xbuf[tid * 64 + d] = (r[d] - mu) * rs * L1g[d] + L1b[d];
    }
    __syncthreads();

    // ff1 (relu)
    for (int idx = tid; idx < S * FF_; idx += 256) {
      int t = idx >> 7, f = idx & 127;
      float acc = B1[f];
      const float* xr = &xbuf[t * 64];
      const float* wr = &W1[f * 64];
#pragma unroll 8
      for (int d = 0; d < 64; ++d) acc += xr[d] * wr[d];
      h1b[idx] = fmaxf(acc, 0.f);
    }
    __syncthreads();

    // ff2 + residual
    for (int idx = tid; idx < S * DM_; idx += 256) {
      int t = idx >> 6, d = idx & 63;
      float acc = B2[d];
      const float* hr = &h1b[t * 128];
      const float* wr = &W2[d * 128];
#pragma unroll 8
      for (int f = 0; f < 128; ++f) acc += hr[f] * wr[f];
      tmpb[idx] = xbuf[idx] + acc;
    }
    __syncthreads();

    // LN2
    if (tid < S) {
      const float* r = &tmpb[tid * 64];
      float mu = 0.f;
      for (int d = 0; d < 64; ++d) mu += r[d];
      mu *= (1.f / 64.f);
      float var = 0.f;
      for (int d = 0; d < 64; ++d) { float u = r[d] - mu; var += u * u; }
      var *= (1.f / 64.f);
      float rs = rsqrtf(var + EPS_);
      for (int d = 0; d < 64; ++d)
        xbuf[tid * 64 + d] = (r[d] - mu) * rs * L2g[d] + L2b[d];
    }
    __syncthreads();
  }

  // classifier on cls token
  if (tid < NC_) {
    float acc = clfb[tid];
    const float* wr = &clfw[tid * DM_];
    for (int d = 0; d < DM_; ++d) acc += xbuf[d] * wr[d];
    out[b * NC_ + tid] = acc;
  }
}

extern "C" void kernel_launch(void* const* d_in, const int* in_sizes, int n_in,
                              void* d_out, int out_size, void* d_ws, size_t ws_size,
                              hipStream_t stream) {
  (void)in_sizes; (void)n_in; (void)out_size; (void)ws_size;
  const float* X    = (const float*)d_in[0];
  const float* A    = (const float*)d_in[1];
  const float* c1w  = (const float*)d_in[2];
  const float* c1b  = (const float*)d_in[3];
  const float* c2w  = (const float*)d_in[4];
  const float* c2b  = (const float*)d_in[5];
  const float* g1W  = (const float*)d_in[6];
  const float* g1q  = (const float*)d_in[7];
  const float* g1g  = (const float*)d_in[8];
  const float* g1b  = (const float*)d_in[9];
  const float* g1m  = (const float*)d_in[10];
  const float* g1v  = (const float*)d_in[11];
  const float* g2W  = (const float*)d_in[12];
  const float* g2q  = (const float*)d_in[13];
  const float* g2g  = (const float*)d_in[14];
  const float* g2b  = (const float*)d_in[15];
  const float* g2m  = (const float*)d_in[16];
  const float* g2v  = (const float*)d_in[17];
  const float* cls  = (const float*)d_in[18];
  const float* pos  = (const float*)d_in[19];
  const float* wqkv = (const float*)d_in[20];
  const float* bqkv = (const float*)d_in[21];
  const float* wo   = (const float*)d_in[22];
  const float* bo   = (const float*)d_in[23];
  const float* ln1g = (const float*)d_in[24];
  const float* ln1b = (const float*)d_in[25];
  const float* w1   = (const float*)d_in[26];
  const float* b1   = (const float*)d_in[27];
  const float* w2   = (const float*)d_in[28];
  const float* b2   = (const float*)d_in[29];
  const float* ln2g = (const float*)d_in[30];
  const float* ln2b = (const float*)d_in[31];
  const float* clfw = (const float*)d_in[32];
  const float* clfb = (const float*)d_in[33];
  float* out = (float*)d_out;

  // workspace layout (floats): Xf[18240*64] | H1[18240*128] | G[960*64] = ~14.3 MB
  float* ws = (float*)d_ws;
  float* Xf = ws;
  float* H1 = Xf + (size_t)B_ * SEG_ * N_ * FIN_;
  float* G  = H1 + (size_t)B_ * SEG_ * N_ * HID_;

  k_temporal<<<B_ * SEG_ * N_, 256, 0, stream>>>(X, c1w, c1b, c2w, c2b, Xf);
  k_gcn1<<<B_ * SEG_, 256, 0, stream>>>(A, Xf, g1W, g1q, g1g, g1b, g1m, g1v, H1);
  k_gcn2<<<B_ * SEG_, 256, 0, stream>>>(A, H1, g2W, g2q, g2g, g2b, g2m, g2v, G);
  k_transformer<<<B_, 256, 0, stream>>>(G, cls, pos, wqkv, bqkv, wo, bo,
                                        ln1g, ln1b, w1, b1, w2, b2, ln2g, ln2b,
                                        clfw, clfb, out);
}

// Round 2
// 381.310 us; speedup vs baseline: 2.0040x; 2.0040x over previous
//
#include <hip/hip_runtime.h>
#include <cmath>

#define B_ 64
#define N_ 19
#define SEG_ 15
#define T_ 400
#define FIN_ 64
#define HID_ 128
#define K_ 4
#define NH_ 4
#define DM_ 64
#define FF_ 128
#define L_ 4
#define NC_ 3
#define EPS_ 1e-5f

typedef __attribute__((ext_vector_type(8))) short bf16x8;
typedef __attribute__((ext_vector_type(4))) short bf16x4;
typedef __attribute__((ext_vector_type(4))) float f32x4;

__device__ __forceinline__ unsigned short f2bf(float x) {
  union { float f; unsigned u; } a; a.f = x;
  unsigned r = a.u + 0x7fffu + ((a.u >> 16) & 1u);
  return (unsigned short)(r >> 16);
}

// ================= k_prep: build BmatT (bf16, [64][296]) and chunk-tiled
// transformer weights W4[k/4][j][4] in workspace. Runs every call. =========
__global__ __launch_bounds__(256) void k_prep(
    const float* __restrict__ c2w,
    const float* __restrict__ wqkv, const float* __restrict__ wo,
    const float* __restrict__ w1, const float* __restrict__ w2,
    unsigned short* __restrict__ bt,
    float* __restrict__ q4, float* __restrict__ wo4,
    float* __restrict__ w14, float* __restrict__ w24) {
  int gid = blockIdx.x * 256 + threadIdx.x;
  if (gid < 18944) {                       // BmatT[oc][kk*32+ic] = c2w[oc][ic][kk]
    int oc = gid / 296, k = gid - oc * 296;
    int ic = k & 31, kk = k >> 5;
    unsigned short v = 0;
    if (kk < 9) v = f2bf(c2w[oc * 288 + ic * 9 + kk]);
    bt[gid] = v;
  } else if (gid < 68096) {                // Wqkv: L x 192 x 64
    int i = gid - 18944;
    int l = i / 12288, r = i % 12288, j = r >> 6, d = r & 63;
    q4[(((l * 16 + (d >> 2)) * 192 + j) << 2) + (d & 3)] = wqkv[i];
  } else if (gid < 84480) {                // Wo: L x 64 x 64
    int i = gid - 68096;
    int l = i / 4096, r = i % 4096, j = r >> 6, d = r & 63;
    wo4[(((l * 16 + (d >> 2)) * 64 + j) << 2) + (d & 3)] = wo[i];
  } else if (gid < 117248) {               // W1: L x 128 x 64
    int i = gid - 84480;
    int l = i / 8192, r = i % 8192, j = r >> 6, d = r & 63;
    w14[(((l * 16 + (d >> 2)) * 128 + j) << 2) + (d & 3)] = w1[i];
  } else if (gid < 150016) {               // W2: L x 64 x 128
    int i = gid - 117248;
    int l = i / 8192, r = i % 8192, j = r >> 7, d = r & 127;
    w24[(((l * 32 + (d >> 2)) * 64 + j) << 2) + (d & 3)] = w2[i];
  }
}

// ================= Kernel 1: temporal encoder =================
// 4 rows per block. conv1 fp32 (hoisted weights) -> p1 bf16 in LDS [pos][ic]
// -> conv2 as MFMA bf16 GEMM (M=64 padded, N=64, K=288) -> pool2+mean.
#define RPB 4
#define ICP 36
#define P1R 40
#define OFFB_XP 37888
#define OFFB_W1 44672
#define OFFB_P1 47872
#define SMEM_T 59392

__global__ __launch_bounds__(256, 2) void k_temporal(
    const float* __restrict__ X, const float* __restrict__ c1w,
    const float* __restrict__ c1b, const float* __restrict__ c2b,
    const float4* __restrict__ bws, float* __restrict__ Xf) {
  __shared__ __align__(16) unsigned char smem[SMEM_T];
  unsigned short* Bsh = (unsigned short*)smem;          // [64][296]
  float* xp  = (float*)(smem + OFFB_XP);                // [4][424]
  float* w1s = (float*)(smem + OFFB_W1);                // [800]
  unsigned short* p1T = (unsigned short*)(smem + OFFB_P1); // [4][40][36]
  float* Dbuf = (float*)(smem + OFFB_XP);               // overlay [64][66]

  const int tid = threadIdx.x;
  const int row0 = blockIdx.x * RPB;

  // ---- stage: BmatT, conv1 weights, zero p1T, input rows ----
  for (int i = tid; i < 2368; i += 256) ((float4*)Bsh)[i] = bws[i];
  for (int i = tid; i < 800; i += 256) w1s[i] = c1w[i];
  for (int i = tid; i < RPB * P1R * ICP / 2; i += 256) ((unsigned*)p1T)[i] = 0u;
  for (int r = 0; r < RPB; ++r) {
    const int gr = row0 + r;
    const int n = gr % N_;
    const int s = (gr / N_) % SEG_;
    const int b = gr / (N_ * SEG_);
    const float* xin = X + (((size_t)b * N_ + n) * SEG_ + s) * T_;
    for (int i = tid; i < 424; i += 256) {
      int t = i - 12;
      xp[r * 424 + i] = (t >= 0 && t < T_) ? xin[t] : 0.f;
    }
  }
  __syncthreads();

  // ---- conv1 + relu + pool4 -> p1T bf16 ----
  {
    const int oc = tid & 31, sub = tid >> 5;
    float wr[25];
#pragma unroll
    for (int k = 0; k < 25; ++k) wr[k] = w1s[oc * 25 + k];
    const float bias = c1b[oc];
    for (int r = 0; r < RPB; ++r) {
      const float* xb = xp + r * 424;
      for (int j = sub; j < 25; j += 8) {
        float xr[37];
#pragma unroll
        for (int k = 0; k < 37; ++k) xr[k] = xb[16 * j + k];
        float m = -1e30f;
#pragma unroll
        for (int p = 0; p < 4; ++p) {
          float acc = bias;
#pragma unroll
          for (int k = 0; k < 25; ++k) acc += xr[4 * p + k] * wr[k];
          m = fmaxf(m, acc);
        }
        p1T[(r * P1R + j + 4) * ICP + oc] = f2bf(fmaxf(m, 0.f));
      }
    }
  }
  __syncthreads();

  // ---- conv2 via MFMA: D[m=(r,op)][oc], K = 9 kk-chunks of 32 ic ----
  const int lane = tid & 63, wv = tid >> 6;
  const int quad = lane >> 4, nl = lane & 15;
  f32x4 acc[4];
  int abase[4];
#pragma unroll
  for (int tm = 0; tm < 4; ++tm) {
    acc[tm] = (f32x4){0.f, 0.f, 0.f, 0.f};
    int m = tm * 16 + nl;
    int rl = m / 14;
    int op = m - rl * 14;
    if (rl > 3) rl = 3;
    abase[tm] = (rl * P1R + 2 * op) * ICP + quad * 8;
  }
  const unsigned short* brow = Bsh + (wv * 16 + nl) * 296 + quad * 8;
  for (int kk = 0; kk < 9; ++kk) {
    bf16x8 bfr = *(const bf16x8*)(brow + kk * 32);
#pragma unroll
    for (int tm = 0; tm < 4; ++tm) {
      const unsigned short* ap = p1T + abase[tm] + kk * ICP;
      union { bf16x4 h[2]; bf16x8 v; } afr;
      afr.h[0] = *(const bf16x4*)ap;
      afr.h[1] = *(const bf16x4*)(ap + 4);
      acc[tm] = __builtin_amdgcn_mfma_f32_16x16x32_bf16(afr.v, bfr, acc[tm], 0, 0, 0);
    }
  }
  __syncthreads();   // p1T/xp dead -> Dbuf overlay safe

#pragma unroll
  for (int tm = 0; tm < 4; ++tm)
#pragma unroll
    for (int rg = 0; rg < 4; ++rg)
      Dbuf[(tm * 16 + quad * 4 + rg) * 66 + wv * 16 + nl] = acc[tm][rg];
  __syncthreads();

  // ---- bias + relu(max pool2) + mean(6) -> Xf ----
  for (int o = tid; o < RPB * 64; o += 256) {
    int rl = o >> 6, oc = o & 63;
    float bias = c2b[oc];
    const float* dr = Dbuf + (rl * 14) * 66 + oc;
    float s = 0.f;
#pragma unroll
    for (int jj = 0; jj < 6; ++jj) {
      float v = fmaxf(dr[(2 * jj) * 66], dr[(2 * jj + 1) * 66]) + bias;
      s += fmaxf(v, 0.f);
    }
    Xf[(size_t)(row0 + rl) * FIN_ + oc] = s * (1.f / 6.f);
  }
}

// ================= Kernel 2: GCN layer 1 =================
__global__ __launch_bounds__(256) void k_gcn1(
    const float* __restrict__ A, const float* __restrict__ Xf,
    const float* __restrict__ W, const float* __restrict__ q,
    const float* __restrict__ bg, const float* __restrict__ bb,
    const float* __restrict__ bm, const float* __restrict__ bv,
    float* __restrict__ H1) {
  const int bs = blockIdx.x;
  const int b = bs / SEG_;
  const int s = bs % SEG_;
  const int tid = threadIdx.x;

  __shared__ float abar[N_ * N_];
  __shared__ float xs[N_ * FIN_];
  __shared__ float wsh[HID_ * 68];
  __shared__ float ybuf[N_ * HID_];
  __shared__ float scale[HID_], shift[HID_];

  float q0 = q[0], q1 = q[1], q2 = q[2], q3 = q[3];
  float mx = fmaxf(fmaxf(q0, q1), fmaxf(q2, q3));
  float e0 = expf(q0 - mx), e1 = expf(q1 - mx), e2 = expf(q2 - mx), e3 = expf(q3 - mx);
  float inv = 1.f / (e0 + e1 + e2 + e3);
  const float a0 = e0 * inv, a1 = e1 * inv, a2 = e2 * inv, a3 = e3 * inv;

  const size_t kstride = (size_t)SEG_ * N_ * N_;
  const float* Ab = A + ((size_t)b * K_ * SEG_ + s) * (N_ * N_);
  for (int i = tid; i < N_ * N_; i += 256)
    abar[i] = a0 * Ab[i] + a1 * Ab[i + kstride] + a2 * Ab[i + 2 * kstride] + a3 * Ab[i + 3 * kstride];

  const float* xb = Xf + (size_t)bs * N_ * FIN_;
  for (int i = tid; i < N_ * FIN_; i += 256) xs[i] = xb[i];

  for (int i = tid; i < HID_ * FIN_; i += 256) wsh[(i >> 6) * 68 + (i & 63)] = W[i];

  for (int o = tid; o < HID_; o += 256) {
    float sc = bg[o] * rsqrtf(bv[o] + EPS_);
    scale[o] = sc;
    shift[o] = bb[o] - bm[o] * sc;
  }
  __syncthreads();

  for (int idx = tid; idx < N_ * HID_; idx += 256) {
    int nn = idx >> 7, o = idx & 127;
    float acc = 0.f;
    const float* xr = &xs[nn * FIN_];
    const float* wr = &wsh[o * 68];
#pragma unroll 8
    for (int f = 0; f < FIN_; ++f) acc += xr[f] * wr[f];
    ybuf[idx] = acc;
  }
  __syncthreads();

  float* Ho = H1 + (size_t)bs * N_ * HID_;
  for (int idx = tid; idx < N_ * HID_; idx += 256) {
    int nn = idx >> 7, o = idx & 127;
    float acc = 0.f;
    const float* ar = &abar[nn * N_];
#pragma unroll
    for (int m = 0; m < N_; ++m) acc += ar[m] * ybuf[m * HID_ + o];
    Ho[idx] = fmaxf(acc * scale[o] + shift[o], 0.f);
  }
}

// ================= Kernel 3: GCN layer 2 + node mean =================
__global__ __launch_bounds__(256) void k_gcn2(
    const float* __restrict__ A, const float* __restrict__ H1,
    const float* __restrict__ W, const float* __restrict__ q,
    const float* __restrict__ bg, const float* __restrict__ bb,
    const float* __restrict__ bm, const float* __restrict__ bv,
    float* __restrict__ G) {
  const int bs = blockIdx.x;
  const int b = bs / SEG_;
  const int s = bs % SEG_;
  const int tid = threadIdx.x;

  __shared__ float abar[N_ * N_];
  __shared__ float hs[N_ * HID_];
  __shared__ float wsh[FIN_ * 132];
  __shared__ float ybuf[N_ * FIN_];
  __shared__ float zbuf[N_ * FIN_];
  __shared__ float scale[FIN_], shift[FIN_];

  float q0 = q[0], q1 = q[1], q2 = q[2], q3 = q[3];
  float mx = fmaxf(fmaxf(q0, q1), fmaxf(q2, q3));
  float e0 = expf(q0 - mx), e1 = expf(q1 - mx), e2 = expf(q2 - mx), e3 = expf(q3 - mx);
  float inv = 1.f / (e0 + e1 + e2 + e3);
  const float a0 = e0 * inv, a1 = e1 * inv, a2 = e2 * inv, a3 = e3 * inv;

  const size_t kstride = (size_t)SEG_ * N_ * N_;
  const float* Ab = A + ((size_t)b * K_ * SEG_ + s) * (N_ * N_);
  for (int i = tid; i < N_ * N_; i += 256)
    abar[i] = a0 * Ab[i] + a1 * Ab[i + kstride] + a2 * Ab[i + 2 * kstride] + a3 * Ab[i + 3 * kstride];

  const float* hb = H1 + (size_t)bs * N_ * HID_;
  for (int i = tid; i < N_ * HID_; i += 256) hs[i] = hb[i];

  for (int i = tid; i < FIN_ * HID_; i += 256) wsh[(i >> 7) * 132 + (i & 127)] = W[i];

  for (int o = tid; o < FIN_; o += 256) {
    float sc = bg[o] * rsqrtf(bv[o] + EPS_);
    scale[o] = sc;
    shift[o] = bb[o] - bm[o] * sc;
  }
  __syncthreads();

  for (int idx = tid; idx < N_ * FIN_; idx += 256) {
    int nn = idx >> 6, o = idx & 63;
    float acc = 0.f;
    const float* hr = &hs[nn * HID_];
    const float* wr = &wsh[o * 132];
#pragma unroll 8
    for (int f = 0; f < HID_; ++f) acc += hr[f] * wr[f];
    ybuf[idx] = acc;
  }
  __syncthreads();

  for (int idx = tid; idx < N_ * FIN_; idx += 256) {
    int nn = idx >> 6, o = idx & 63;
    float acc = 0.f;
    const float* ar = &abar[nn * N_];
#pragma unroll
    for (int m = 0; m < N_; ++m) acc += ar[m] * ybuf[m * FIN_ + o];
    zbuf[idx] = fmaxf(acc * scale[o] + shift[o], 0.f);
  }
  __syncthreads();

  if (tid < FIN_) {
    float ssum = 0.f;
#pragma unroll
    for (int nn = 0; nn < N_; ++nn) ssum += zbuf[nn * FIN_ + tid];
    G[(size_t)bs * FIN_ + tid] = ssum * (1.f / (float)N_);
  }
}

// ================= Kernel 4: transformer + classifier =================
__global__ __launch_bounds__(256) void k_transformer(
    const float* __restrict__ G, const float* __restrict__ cls,
    const float* __restrict__ pos,
    const float4* __restrict__ Wq4, const float4* __restrict__ Wo4,
    const float4* __restrict__ W14, const float4* __restrict__ W24,
    const float* __restrict__ bqkv, const float* __restrict__ bo,
    const float* __restrict__ ln1g, const float* __restrict__ ln1b,
    const float* __restrict__ b1, const float* __restrict__ b2,
    const float* __restrict__ ln2g, const float* __restrict__ ln2b,
    const float* __restrict__ clfw, const float* __restrict__ clfb,
    float* __restrict__ out) {
  const int b = blockIdx.x;
  const int tid = threadIdx.x;

  __shared__ float xbuf[16 * 64];
  __shared__ float qkvb[16 * 196];
  __shared__ float scb[NH_ * 16 * 16];
  __shared__ float obuf[16 * 64];
  __shared__ float h1b[16 * 132];
  __shared__ float tmpb[16 * 64];

  for (int i = tid; i < 16 * 64; i += 256) {
    int t = i >> 6, d = i & 63;
    float base = (t == 0) ? cls[d] : G[((size_t)b * SEG_ + (t - 1)) * DM_ + d];
    xbuf[i] = base + pos[t * DM_ + d];
  }
  __syncthreads();

  const int j = tid;
  for (int l = 0; l < L_; ++l) {
    const float4* wq = Wq4 + (size_t)l * 3072;
    const float4* wop = Wo4 + (size_t)l * 1024;
    const float4* w1p = W14 + (size_t)l * 2048;
    const float4* w2p = W24 + (size_t)l * 2048;

    // ---- qkv = x @ Wqkv^T + b ----
    float bq = (j < 192) ? bqkv[l * 192 + j] : 0.f;
    for (int t = 0; t < 16; ++t) {
      if (j < 192) {
        float acc = bq;
        const float4* xb4 = (const float4*)(xbuf + t * 64);
#pragma unroll
        for (int c = 0; c < 16; ++c) {
          float4 w = wq[c * 192 + j];
          float4 x = xb4[c];
          acc += w.x * x.x + w.y * x.y + w.z * x.z + w.w * x.w;
        }
        qkvb[t * 196 + j] = acc;
      }
    }
    __syncthreads();

    // ---- scores ----
    for (int idx = tid; idx < 1024; idx += 256) {
      int h = idx >> 8, t = (idx >> 4) & 15, u = idx & 15;
      const float* qr = &qkvb[t * 196 + h * 16];
      const float* kr = &qkvb[u * 196 + 64 + h * 16];
      float acc = 0.f;
#pragma unroll
      for (int d = 0; d < 16; ++d) acc += qr[d] * kr[d];
      scb[idx] = acc * 0.25f;
    }
    __syncthreads();

    // ---- softmax (4 lanes per row) ----
    {
      int row = tid >> 2, qq = tid & 3;
      float* r = &scb[row * 16 + qq * 4];
      float v0 = r[0], v1 = r[1], v2 = r[2], v3 = r[3];
      float mxv = fmaxf(fmaxf(v0, v1), fmaxf(v2, v3));
      mxv = fmaxf(mxv, __shfl_xor(mxv, 1));
      mxv = fmaxf(mxv, __shfl_xor(mxv, 2));
      v0 = expf(v0 - mxv); v1 = expf(v1 - mxv);
      v2 = expf(v2 - mxv); v3 = expf(v3 - mxv);
      float sum = v0 + v1 + v2 + v3;
      sum += __shfl_xor(sum, 1);
      sum += __shfl_xor(sum, 2);
      float is = 1.f / sum;
      r[0] = v0 * is; r[1] = v1 * is; r[2] = v2 * is; r[3] = v3 * is;
    }
    __syncthreads();

    // ---- o = attn @ v ----
    for (int idx = tid; idx < 1024; idx += 256) {
      int t = idx >> 6, e = idx & 63, h = e >> 4, d = e & 15;
      const float* pr = &scb[(h * 16 + t) * 16];
      float acc = 0.f;
#pragma unroll
      for (int u = 0; u < 16; ++u) acc += pr[u] * qkvb[u * 196 + 128 + h * 16 + d];
      obuf[idx] = acc;
    }
    __syncthreads();

    // ---- proj + residual ----
    for (int idx = tid; idx < 1024; idx += 256) {
      int t = idx >> 6, d = idx & 63;
      float acc = bo[l * 64 + d];
      const float4* ob4 = (const float4*)(obuf + t * 64);
#pragma unroll
      for (int c = 0; c < 16; ++c) {
        float4 w = wop[c * 64 + d];
        float4 x = ob4[c];
        acc += w.x * x.x + w.y * x.y + w.z * x.z + w.w * x.w;
      }
      tmpb[idx] = xbuf[idx] + acc;
    }
    __syncthreads();

    // ---- LN1 (16 lanes per token) ----
    {
      int t = tid >> 4, i2 = tid & 15;
      float4 v = ((const float4*)(tmpb + t * 64))[i2];
      float s = v.x + v.y + v.z + v.w;
      s += __shfl_xor(s, 1); s += __shfl_xor(s, 2);
      s += __shfl_xor(s, 4); s += __shfl_xor(s, 8);
      float mu = s * (1.f / 64.f);
      float d0 = v.x - mu, d1 = v.y - mu, d2 = v.z - mu, d3 = v.w - mu;
      float vr = d0 * d0 + d1 * d1 + d2 * d2 + d3 * d3;
      vr += __shfl_xor(vr, 1); vr += __shfl_xor(vr, 2);
      vr += __shfl_xor(vr, 4); vr += __shfl_xor(vr, 8);
      float rs = rsqrtf(vr * (1.f / 64.f) + EPS_);
      float4 g4 = ((const float4*)(ln1g + l * 64))[i2];
      float4 b4 = ((const float4*)(ln1b + l * 64))[i2];
      float4 o4;
      o4.x = d0 * rs * g4.x + b4.x; o4.y = d1 * rs * g4.y + b4.y;
      o4.z = d2 * rs * g4.z + b4.z; o4.w = d3 * rs * g4.w + b4.w;
      ((float4*)(xbuf + t * 64))[i2] = o4;
    }
    __syncthreads();

    // ---- ff1 (relu) ----
    for (int idx = tid; idx < 2048; idx += 256) {
      int t = idx >> 7, f = idx & 127;
      float acc = b1[l * 128 + f];
      const float4* xb4 = (const float4*)(xbuf + t * 64);
#pragma unroll
      for (int c = 0; c < 16; ++c) {
        float4 w = w1p[c * 128 + f];
        float4 x = xb4[c];
        acc += w.x * x.x + w.y * x.y + w.z * x.z + w.w * x.w;
      }
      h1b[t * 132 + f] = fmaxf(acc, 0.f);
    }
    __syncthreads();

    // ---- ff2 + residual ----
    for (int idx = tid; idx < 1024; idx += 256) {
      int t = idx >> 6, d = idx & 63;
      float acc = b2[l * 64 + d];
      const float4* hb4 = (const float4*)(h1b + t * 132);
#pragma unroll
      for (int c = 0; c < 32; ++c) {
        float4 w = w2p[c * 64 + d];
        float4 x = hb4[c];
        acc += w.x * x.x + w.y * x.y + w.z * x.z + w.w * x.w;
      }
      tmpb[idx] = xbuf[idx] + acc;
    }
    __syncthreads();

    // ---- LN2 ----
    {
      int t = tid >> 4, i2 = tid & 15;
      float4 v = ((const float4*)(tmpb + t * 64))[i2];
      float s = v.x + v.y + v.z + v.w;
      s += __shfl_xor(s, 1); s += __shfl_xor(s, 2);
      s += __shfl_xor(s, 4); s += __shfl_xor(s, 8);
      float mu = s * (1.f / 64.f);
      float d0 = v.x - mu, d1 = v.y - mu, d2 = v.z - mu, d3 = v.w - mu;
      float vr = d0 * d0 + d1 * d1 + d2 * d2 + d3 * d3;
      vr += __shfl_xor(vr, 1); vr += __shfl_xor(vr, 2);
      vr += __shfl_xor(vr, 4); vr += __shfl_xor(vr, 8);
      float rs = rsqrtf(vr * (1.f / 64.f) + EPS_);
      float4 g4 = ((const float4*)(ln2g + l * 64))[i2];
      float4 b4 = ((const float4*)(ln2b + l * 64))[i2];
      float4 o4;
      o4.x = d0 * rs * g4.x + b4.x; o4.y = d1 * rs * g4.y + b4.y;
      o4.z = d2 * rs * g4.z + b4.z; o4.w = d3 * rs * g4.w + b4.w;
      ((float4*)(xbuf + t * 64))[i2] = o4;
    }
    __syncthreads();
  }

  if (tid < NC_) {
    float acc = clfb[tid];
    const float* wr = &clfw[tid * DM_];
    for (int d = 0; d < DM_; ++d) acc += xbuf[d] * wr[d];
    out[b * NC_ + tid] = acc;
  }
}

extern "C" void kernel_launch(void* const* d_in, const int* in_sizes, int n_in,
                              void* d_out, int out_size, void* d_ws, size_t ws_size,
                              hipStream_t stream) {
  (void)in_sizes; (void)n_in; (void)out_size; (void)ws_size;
  const float* X    = (const float*)d_in[0];
  const float* A    = (const float*)d_in[1];
  const float* c1w  = (const float*)d_in[2];
  const float* c1b  = (const float*)d_in[3];
  const float* c2w  = (const float*)d_in[4];
  const float* c2b  = (const float*)d_in[5];
  const float* g1W  = (const float*)d_in[6];
  const float* g1q  = (const float*)d_in[7];
  const float* g1g  = (const float*)d_in[8];
  const float* g1b  = (const float*)d_in[9];
  const float* g1m  = (const float*)d_in[10];
  const float* g1v  = (const float*)d_in[11];
  const float* g2W  = (const float*)d_in[12];
  const float* g2q  = (const float*)d_in[13];
  const float* g2g  = (const float*)d_in[14];
  const float* g2b  = (const float*)d_in[15];
  const float* g2m  = (const float*)d_in[16];
  const float* g2v  = (const float*)d_in[17];
  const float* cls  = (const float*)d_in[18];
  const float* pos  = (const float*)d_in[19];
  const float* wqkv = (const float*)d_in[20];
  const float* bqkv = (const float*)d_in[21];
  const float* wo   = (const float*)d_in[22];
  const float* bo   = (const float*)d_in[23];
  const float* ln1g = (const float*)d_in[24];
  const float* ln1b = (const float*)d_in[25];
  const float* w1   = (const float*)d_in[26];
  const float* b1   = (const float*)d_in[27];
  const float* w2   = (const float*)d_in[28];
  const float* b2   = (const float*)d_in[29];
  const float* ln2g = (const float*)d_in[30];
  const float* ln2b = (const float*)d_in[31];
  const float* clfw = (const float*)d_in[32];
  const float* clfb = (const float*)d_in[33];
  float* out = (float*)d_out;

  // ---- workspace layout (bytes) ----
  char* wsb = (char*)d_ws;
  unsigned short* BmatT = (unsigned short*)(wsb + 0);        //  37888
  float* Wq4  = (float*)(wsb + 37888);                       // 196608
  float* Wo4  = (float*)(wsb + 234496);                      //  65536
  float* W14  = (float*)(wsb + 300032);                      // 131072
  float* W24  = (float*)(wsb + 431104);                      // 131072
  float* Xf   = (float*)(wsb + 562176);                      // 4669440
  float* H1   = (float*)(wsb + 5231616);                     // 9338880
  float* G    = (float*)(wsb + 14570496);                    //  245760 -> ~14.8 MB

  k_prep<<<586, 256, 0, stream>>>(c2w, wqkv, wo, w1, w2,
                                  BmatT, Wq4, Wo4, W14, W24);
  k_temporal<<<B_ * SEG_ * N_ / RPB, 256, 0, stream>>>(
      X, c1w, c1b, c2b, (const float4*)BmatT, Xf);
  k_gcn1<<<B_ * SEG_, 256, 0, stream>>>(A, Xf, g1W, g1q, g1g, g1b, g1m, g1v, H1);
  k_gcn2<<<B_ * SEG_, 256, 0, stream>>>(A, H1, g2W, g2q, g2g, g2b, g2m, g2v, G);
  k_transformer<<<B_, 256, 0, stream>>>(G, cls, pos,
                                        (const float4*)Wq4, (const float4*)Wo4,
                                        (const float4*)W14, (const float4*)W24,
                                        bqkv, bo, ln1g, ln1b, b1, b2, ln2g, ln2b,
                                        clfw, clfb, out);
}

// Round 3
// 290.672 us; speedup vs baseline: 2.6288x; 1.3118x over previous
//
#include <hip/hip_runtime.h>
#include <cmath>

#define B_ 64
#define N_ 19
#define SEG_ 15
#define T_ 400
#define FIN_ 64
#define HID_ 128
#define K_ 4
#define NH_ 4
#define DM_ 64
#define FF_ 128
#define L_ 4
#define NC_ 3
#define EPS_ 1e-5f

typedef __attribute__((ext_vector_type(8))) short bf16x8;
typedef __attribute__((ext_vector_type(4))) float f32x4;
typedef unsigned short ushort_t;

__device__ __forceinline__ ushort_t f2bf(float x) {
  union { float f; unsigned u; } a; a.f = x;
  unsigned r = a.u + 0x7fffu + ((a.u >> 16) & 1u);
  return (ushort_t)(r >> 16);
}
__device__ __forceinline__ float bf2f(ushort_t h) {
  union { unsigned u; float f; } a; a.u = ((unsigned)h) << 16;
  return a.f;
}

// ================= k_prep =================
// BmatT[oc][296] bf16 (conv2 B), chunk-tiled fp32 transformer weights,
// hi/lo bf16 splits of GCN weights.
__global__ __launch_bounds__(256) void k_prep(
    const float* __restrict__ c2w,
    const float* __restrict__ wqkv, const float* __restrict__ wo,
    const float* __restrict__ w1, const float* __restrict__ w2,
    const float* __restrict__ g1W, const float* __restrict__ g2W,
    ushort_t* __restrict__ bt,
    float* __restrict__ q4, float* __restrict__ wo4,
    float* __restrict__ w14, float* __restrict__ w24,
    ushort_t* __restrict__ W1h, ushort_t* __restrict__ W1l,
    ushort_t* __restrict__ W2h, ushort_t* __restrict__ W2l) {
  int gid = blockIdx.x * 256 + threadIdx.x;
  if (gid < 18944) {                       // BmatT[oc][kk*32+ic] = c2w[oc][ic][kk]
    int oc = gid / 296, k = gid - oc * 296;
    int ic = k & 31, kk = k >> 5;
    ushort_t v = 0;
    if (kk < 9) v = f2bf(c2w[oc * 288 + ic * 9 + kk]);
    bt[gid] = v;
  } else if (gid < 68096) {                // Wqkv: L x 192 x 64
    int i = gid - 18944;
    int l = i / 12288, r = i % 12288, j = r >> 6, d = r & 63;
    q4[(((l * 16 + (d >> 2)) * 192 + j) << 2) + (d & 3)] = wqkv[i];
  } else if (gid < 84480) {                // Wo: L x 64 x 64
    int i = gid - 68096;
    int l = i / 4096, r = i % 4096, j = r >> 6, d = r & 63;
    wo4[(((l * 16 + (d >> 2)) * 64 + j) << 2) + (d & 3)] = wo[i];
  } else if (gid < 117248) {               // W1: L x 128 x 64
    int i = gid - 84480;
    int l = i / 8192, r = i % 8192, j = r >> 6, d = r & 63;
    w14[(((l * 16 + (d >> 2)) * 128 + j) << 2) + (d & 3)] = w1[i];
  } else if (gid < 150016) {               // W2: L x 64 x 128
    int i = gid - 117248;
    int l = i / 8192, r = i % 8192, j = r >> 7, d = r & 127;
    w24[(((l * 32 + (d >> 2)) * 64 + j) << 2) + (d & 3)] = w2[i];
  } else if (gid < 158208) {               // g1_W split hi/lo [128][64]
    int i = gid - 150016;
    float v = g1W[i];
    ushort_t h = f2bf(v);
    W1h[i] = h;
    W1l[i] = f2bf(v - bf2f(h));
  } else if (gid < 166400) {               // g2_W split hi/lo [64][128]
    int i = gid - 158208;
    float v = g2W[i];
    ushort_t h = f2bf(v);
    W2h[i] = h;
    W2l[i] = f2bf(v - bf2f(h));
  }
}

// ================= Kernel 1: temporal encoder =================
// 4 rows per block. conv1 fp32 -> p1 bf16 LDS [pos][ic] (stride 40 ushorts,
// 16B-aligned rows -> single ds_read_b128 A-frags, uniform bank spread).
// conv2 = MFMA bf16 GEMM with B-frags read directly from global (L2).
#define RPB 4
#define ICP 40
#define P1R 40
#define OFFB_XP 0
#define OFFB_W1 6784
#define OFFB_P1 9984
#define SMEM_T 22784

__global__ __launch_bounds__(256, 4) void k_temporal(
    const float* __restrict__ X, const float* __restrict__ c1w,
    const float* __restrict__ c1b, const float* __restrict__ c2b,
    const ushort_t* __restrict__ BmatT, float* __restrict__ Xf) {
  __shared__ __align__(16) unsigned char smem[SMEM_T];
  float* xp  = (float*)(smem + OFFB_XP);                   // [4][424]
  float* w1s = (float*)(smem + OFFB_W1);                   // [800]
  ushort_t* p1T = (ushort_t*)(smem + OFFB_P1);             // [4*40][40]
  float* Dbuf = (float*)(smem + OFFB_XP);                  // overlay [64][66]

  const int tid = threadIdx.x;
  const int row0 = blockIdx.x * RPB;

  for (int i = tid; i < 800; i += 256) w1s[i] = c1w[i];
  for (int i = tid; i < RPB * P1R * ICP / 2; i += 256) ((unsigned*)p1T)[i] = 0u;
  for (int r = 0; r < RPB; ++r) {
    const int gr = row0 + r;
    const int n = gr % N_;
    const int s = (gr / N_) % SEG_;
    const int b = gr / (N_ * SEG_);
    const float* xin = X + (((size_t)b * N_ + n) * SEG_ + s) * T_;
    for (int i = tid; i < 424; i += 256) {
      int t = i - 12;
      xp[r * 424 + i] = (t >= 0 && t < T_) ? xin[t] : 0.f;
    }
  }
  __syncthreads();

  // ---- conv1 + relu + pool4 -> p1T bf16 ----
  {
    const int oc = tid & 31, sub = tid >> 5;
    float wr[25];
#pragma unroll
    for (int k = 0; k < 25; ++k) wr[k] = w1s[oc * 25 + k];
    const float bias = c1b[oc];
    for (int r = 0; r < RPB; ++r) {
      const float* xb = xp + r * 424;
      for (int j = sub; j < 25; j += 8) {
        float xr[37];
#pragma unroll
        for (int k = 0; k < 37; ++k) xr[k] = xb[16 * j + k];
        float m = -1e30f;
#pragma unroll
        for (int p = 0; p < 4; ++p) {
          float acc = bias;
#pragma unroll
          for (int k = 0; k < 25; ++k) acc += xr[4 * p + k] * wr[k];
          m = fmaxf(m, acc);
        }
        p1T[(r * P1R + j + 4) * ICP + oc] = f2bf(fmaxf(m, 0.f));
      }
    }
  }
  __syncthreads();

  // ---- conv2 via MFMA ----
  const int lane = tid & 63, wv = tid >> 6;
  const int quad = lane >> 4, nl = lane & 15;
  f32x4 acc[4];
  int abase[4];
#pragma unroll
  for (int tm = 0; tm < 4; ++tm) {
    acc[tm] = (f32x4){0.f, 0.f, 0.f, 0.f};
    int m = tm * 16 + nl;
    int rl = m / 14;
    int op = m - rl * 14;
    if (rl > 3) rl = 3;
    if (op > 13) op = 13;
    abase[tm] = (rl * P1R + 2 * op) * ICP + quad * 8;
  }
  const ushort_t* brow = BmatT + (wv * 16 + nl) * 296 + quad * 8;
#pragma unroll
  for (int kk = 0; kk < 9; ++kk) {
    bf16x8 bfr = *(const bf16x8*)(brow + kk * 32);     // global (L2)
#pragma unroll
    for (int tm = 0; tm < 4; ++tm) {
      bf16x8 afr = *(const bf16x8*)(p1T + abase[tm] + kk * ICP);  // ds_read_b128
      acc[tm] = __builtin_amdgcn_mfma_f32_16x16x32_bf16(afr, bfr, acc[tm], 0, 0, 0);
    }
  }
  __syncthreads();   // p1T/xp dead -> Dbuf overlay safe

#pragma unroll
  for (int tm = 0; tm < 4; ++tm)
#pragma unroll
    for (int rg = 0; rg < 4; ++rg)
      Dbuf[(tm * 16 + quad * 4 + rg) * 66 + wv * 16 + nl] = acc[tm][rg];
  __syncthreads();

  for (int o = tid; o < RPB * 64; o += 256) {
    int rl = o >> 6, oc = o & 63;
    float bias = c2b[oc];
    const float* dr = Dbuf + (rl * 14) * 66 + oc;
    float s = 0.f;
#pragma unroll
    for (int jj = 0; jj < 6; ++jj) {
      float v = fmaxf(dr[(2 * jj) * 66], dr[(2 * jj + 1) * 66]) + bias;
      s += fmaxf(v, 0.f);
    }
    Xf[(size_t)(row0 + rl) * FIN_ + oc] = s * (1.f / 6.f);
  }
}

// ================= Kernel 2: fused GCN (both layers) =================
// Per (b,s). Weight GEMMs via bf16x3-split MFMA (fp32-class precision);
// abar diffusion + BN + relu in fp32; node-mean epilogue -> G.
__global__ __launch_bounds__(256) void k_gcn(
    const float* __restrict__ A, const float* __restrict__ Xf,
    const ushort_t* __restrict__ W1h, const ushort_t* __restrict__ W1l,
    const ushort_t* __restrict__ W2h, const ushort_t* __restrict__ W2l,
    const float* __restrict__ q1, const float* __restrict__ q2,
    const float* __restrict__ b1g, const float* __restrict__ b1b,
    const float* __restrict__ b1m, const float* __restrict__ b1v,
    const float* __restrict__ b2g, const float* __restrict__ b2b,
    const float* __restrict__ b2m, const float* __restrict__ b2v,
    float* __restrict__ G) {
  const int bs = blockIdx.x;
  const int b = bs / SEG_;
  const int s = bs % SEG_;
  const int tid = threadIdx.x;

  __shared__ __align__(16) ushort_t xh[32 * 72], xl[32 * 72];      // X hi/lo
  __shared__ __align__(16) ushort_t Hh[32 * 136], Hl[32 * 136];    // H hi/lo
  __shared__ float abar1[N_ * N_], abar2[N_ * N_];
  __shared__ float ybuf[N_ * 130];
  __shared__ float zbuf[N_ * 64];
  __shared__ float sc1[HID_], sh1[HID_], sc2[FIN_], sh2[FIN_];

  // ---- alphas & combined adjacency for both layers ----
  {
    float p0 = q1[0], p1 = q1[1], p2 = q1[2], p3 = q1[3];
    float mx = fmaxf(fmaxf(p0, p1), fmaxf(p2, p3));
    float e0 = expf(p0 - mx), e1 = expf(p1 - mx), e2 = expf(p2 - mx), e3 = expf(p3 - mx);
    float inv = 1.f / (e0 + e1 + e2 + e3);
    float a0 = e0 * inv, a1 = e1 * inv, a2 = e2 * inv, a3 = e3 * inv;
    float r0 = q2[0], r1 = q2[1], r2 = q2[2], r3 = q2[3];
    float mx2 = fmaxf(fmaxf(r0, r1), fmaxf(r2, r3));
    float f0 = expf(r0 - mx2), f1 = expf(r1 - mx2), f2 = expf(r2 - mx2), f3 = expf(r3 - mx2);
    float inv2 = 1.f / (f0 + f1 + f2 + f3);
    float c0 = f0 * inv2, c1 = f1 * inv2, c2 = f2 * inv2, c3 = f3 * inv2;
    const size_t kstride = (size_t)SEG_ * N_ * N_;
    const float* Ab = A + ((size_t)b * K_ * SEG_ + s) * (N_ * N_);
    for (int i = tid; i < N_ * N_; i += 256) {
      float v0 = Ab[i], v1 = Ab[i + kstride], v2 = Ab[i + 2 * kstride], v3 = Ab[i + 3 * kstride];
      abar1[i] = a0 * v0 + a1 * v1 + a2 * v2 + a3 * v3;
      abar2[i] = c0 * v0 + c1 * v1 + c2 * v2 + c3 * v3;
    }
  }

  // ---- zero hi/lo buffers (pad rows/cols), stage X split ----
  for (int i = tid; i < 32 * 72 / 2; i += 256) {
    ((unsigned*)xh)[i] = 0u; ((unsigned*)xl)[i] = 0u;
  }
  for (int i = tid; i < 32 * 136 / 2; i += 256) {
    ((unsigned*)Hh)[i] = 0u; ((unsigned*)Hl)[i] = 0u;
  }
  for (int o = tid; o < HID_; o += 256) {
    float sc = b1g[o] * rsqrtf(b1v[o] + EPS_);
    sc1[o] = sc; sh1[o] = b1b[o] - b1m[o] * sc;
  }
  for (int o = tid; o < FIN_; o += 256) {
    float sc = b2g[o] * rsqrtf(b2v[o] + EPS_);
    sc2[o] = sc; sh2[o] = b2b[o] - b2m[o] * sc;
  }
  __syncthreads();

  const float* xb = Xf + (size_t)bs * N_ * FIN_;
  for (int i = tid; i < N_ * FIN_; i += 256) {
    int r = i >> 6, f = i & 63;
    float v = xb[i];
    ushort_t h = f2bf(v);
    xh[r * 72 + f] = h;
    xl[r * 72 + f] = f2bf(v - bf2f(h));
  }
  __syncthreads();

  const int lane = tid & 63, wv = tid >> 6;
  const int quad = lane >> 4, nl = lane & 15;

  // ---- GEMM1: ybuf[19x128] = X @ W1^T (bf16x3) ----
#pragma unroll
  for (int mt = 0; mt < 2; ++mt) {
#pragma unroll
    for (int ntl = 0; ntl < 2; ++ntl) {
      const int nt = wv * 2 + ntl;
      f32x4 acc = (f32x4){0.f, 0.f, 0.f, 0.f};
#pragma unroll
      for (int ks = 0; ks < 2; ++ks) {
        bf16x8 ah = *(const bf16x8*)(xh + (mt * 16 + nl) * 72 + ks * 32 + quad * 8);
        bf16x8 al = *(const bf16x8*)(xl + (mt * 16 + nl) * 72 + ks * 32 + quad * 8);
        bf16x8 bh = *(const bf16x8*)(W1h + (nt * 16 + nl) * 64 + ks * 32 + quad * 8);
        bf16x8 bl = *(const bf16x8*)(W1l + (nt * 16 + nl) * 64 + ks * 32 + quad * 8);
        acc = __builtin_amdgcn_mfma_f32_16x16x32_bf16(ah, bh, acc, 0, 0, 0);
        acc = __builtin_amdgcn_mfma_f32_16x16x32_bf16(al, bh, acc, 0, 0, 0);
        acc = __builtin_amdgcn_mfma_f32_16x16x32_bf16(ah, bl, acc, 0, 0, 0);
      }
#pragma unroll
      for (int r = 0; r < 4; ++r) {
        int m = mt * 16 + quad * 4 + r;
        if (m < N_) ybuf[m * 130 + nt * 16 + nl] = acc[r];
      }
    }
  }
  __syncthreads();

  // ---- diffusion 1 + BN + relu -> H split hi/lo ----
  for (int idx = tid; idx < N_ * HID_; idx += 256) {
    int nn = idx >> 7, o = idx & 127;
    float acc = 0.f;
    const float* ar = &abar1[nn * N_];
#pragma unroll
    for (int m = 0; m < N_; ++m) acc += ar[m] * ybuf[m * 130 + o];
    float h = fmaxf(acc * sc1[o] + sh1[o], 0.f);
    ushort_t hh = f2bf(h);
    Hh[nn * 136 + o] = hh;
    Hl[nn * 136 + o] = f2bf(h - bf2f(hh));
  }
  __syncthreads();

  // ---- GEMM2: ybuf[19x64] = H @ W2^T (bf16x3), reuse ybuf stride 66 ----
  {
    const int nt = wv;
#pragma unroll
    for (int mt = 0; mt < 2; ++mt) {
      f32x4 acc = (f32x4){0.f, 0.f, 0.f, 0.f};
#pragma unroll
      for (int ks = 0; ks < 4; ++ks) {
        bf16x8 ah = *(const bf16x8*)(Hh + (mt * 16 + nl) * 136 + ks * 32 + quad * 8);
        bf16x8 al = *(const bf16x8*)(Hl + (mt * 16 + nl) * 136 + ks * 32 + quad * 8);
        bf16x8 bh = *(const bf16x8*)(W2h + (nt * 16 + nl) * 128 + ks * 32 + quad * 8);
        bf16x8 bl = *(const bf16x8*)(W2l + (nt * 16 + nl) * 128 + ks * 32 + quad * 8);
        acc = __builtin_amdgcn_mfma_f32_16x16x32_bf16(ah, bh, acc, 0, 0, 0);
        acc = __builtin_amdgcn_mfma_f32_16x16x32_bf16(al, bh, acc, 0, 0, 0);
        acc = __builtin_amdgcn_mfma_f32_16x16x32_bf16(ah, bl, acc, 0, 0, 0);
      }
#pragma unroll
      for (int r = 0; r < 4; ++r) {
        int m = mt * 16 + quad * 4 + r;
        if (m < N_) ybuf[m * 66 + nt * 16 + nl] = acc[r];
      }
    }
  }
  __syncthreads();

  // ---- diffusion 2 + BN + relu -> zbuf ----
  for (int idx = tid; idx < N_ * FIN_; idx += 256) {
    int nn = idx >> 6, o = idx & 63;
    float acc = 0.f;
    const float* ar = &abar2[nn * N_];
#pragma unroll
    for (int m = 0; m < N_; ++m) acc += ar[m] * ybuf[m * 66 + o];
    zbuf[idx] = fmaxf(acc * sc2[o] + sh2[o], 0.f);
  }
  __syncthreads();

  // ---- node mean -> G ----
  if (tid < FIN_) {
    float ssum = 0.f;
#pragma unroll
    for (int nn = 0; nn < N_; ++nn) ssum += zbuf[nn * 64 + tid];
    G[(size_t)bs * FIN_ + tid] = ssum * (1.f / (float)N_);
  }
}

// ================= Kernel 3: transformer + classifier =================
// 4-token register tiling in all weight GEMMs: weight traffic /4.
__global__ __launch_bounds__(256) void k_transformer(
    const float* __restrict__ G, const float* __restrict__ cls,
    const float* __restrict__ pos,
    const float4* __restrict__ Wq4, const float4* __restrict__ Wo4,
    const float4* __restrict__ W14, const float4* __restrict__ W24,
    const float* __restrict__ bqkv, const float* __restrict__ bo,
    const float* __restrict__ ln1g, const float* __restrict__ ln1b,
    const float* __restrict__ b1, const float* __restrict__ b2,
    const float* __restrict__ ln2g, const float* __restrict__ ln2b,
    const float* __restrict__ clfw, const float* __restrict__ clfb,
    float* __restrict__ out) {
  const int b = blockIdx.x;
  const int tid = threadIdx.x;

  __shared__ float xbuf[16 * 64];
  __shared__ float qkvb[16 * 196];
  __shared__ float scb[NH_ * 16 * 16];
  __shared__ float obuf[16 * 64];
  __shared__ float h1b[16 * 132];
  __shared__ float tmpb[16 * 64];

  for (int i = tid; i < 16 * 64; i += 256) {
    int t = i >> 6, d = i & 63;
    float base = (t == 0) ? cls[d] : G[((size_t)b * SEG_ + (t - 1)) * DM_ + d];
    xbuf[i] = base + pos[t * DM_ + d];
  }
  __syncthreads();

  for (int l = 0; l < L_; ++l) {
    const float4* wq = Wq4 + (size_t)l * 3072;
    const float4* wop = Wo4 + (size_t)l * 1024;
    const float4* w1p = W14 + (size_t)l * 2048;
    const float4* w2p = W24 + (size_t)l * 2048;

    // ---- qkv = x @ Wqkv^T + b  (4t per thread) ----
    for (int idx = tid; idx < 768; idx += 256) {
      int j = idx % 192, tg = idx / 192;
      float bqv = bqkv[l * 192 + j];
      float a0 = bqv, a1 = bqv, a2 = bqv, a3 = bqv;
      const float4* xb4 = (const float4*)xbuf;
#pragma unroll
      for (int c = 0; c < 16; ++c) {
        float4 w = wq[c * 192 + j];
        float4 x0 = xb4[(tg * 4 + 0) * 16 + c];
        float4 x1 = xb4[(tg * 4 + 1) * 16 + c];
        float4 x2 = xb4[(tg * 4 + 2) * 16 + c];
        float4 x3 = xb4[(tg * 4 + 3) * 16 + c];
        a0 += w.x * x0.x + w.y * x0.y + w.z * x0.z + w.w * x0.w;
        a1 += w.x * x1.x + w.y * x1.y + w.z * x1.z + w.w * x1.w;
        a2 += w.x * x2.x + w.y * x2.y + w.z * x2.z + w.w * x2.w;
        a3 += w.x * x3.x + w.y * x3.y + w.z * x3.z + w.w * x3.w;
      }
      qkvb[(tg * 4 + 0) * 196 + j] = a0;
      qkvb[(tg * 4 + 1) * 196 + j] = a1;
      qkvb[(tg * 4 + 2) * 196 + j] = a2;
      qkvb[(tg * 4 + 3) * 196 + j] = a3;
    }
    __syncthreads();

    // ---- scores ----
    for (int idx = tid; idx < 1024; idx += 256) {
      int h = idx >> 8, t = (idx >> 4) & 15, u = idx & 15;
      const float* qr = &qkvb[t * 196 + h * 16];
      const float* kr = &qkvb[u * 196 + 64 + h * 16];
      float acc = 0.f;
#pragma unroll
      for (int d = 0; d < 16; ++d) acc += qr[d] * kr[d];
      scb[idx] = acc * 0.25f;
    }
    __syncthreads();

    // ---- softmax (4 lanes per row) ----
    {
      int row = tid >> 2, qq = tid & 3;
      float* r = &scb[row * 16 + qq * 4];
      float v0 = r[0], v1 = r[1], v2 = r[2], v3 = r[3];
      float mxv = fmaxf(fmaxf(v0, v1), fmaxf(v2, v3));
      mxv = fmaxf(mxv, __shfl_xor(mxv, 1));
      mxv = fmaxf(mxv, __shfl_xor(mxv, 2));
      v0 = expf(v0 - mxv); v1 = expf(v1 - mxv);
      v2 = expf(v2 - mxv); v3 = expf(v3 - mxv);
      float sum = v0 + v1 + v2 + v3;
      sum += __shfl_xor(sum, 1);
      sum += __shfl_xor(sum, 2);
      float is = 1.f / sum;
      r[0] = v0 * is; r[1] = v1 * is; r[2] = v2 * is; r[3] = v3 * is;
    }
    __syncthreads();

    // ---- o = attn @ v ----
    for (int idx = tid; idx < 1024; idx += 256) {
      int t = idx >> 6, e = idx & 63, h = e >> 4, d = e & 15;
      const float* pr = &scb[(h * 16 + t) * 16];
      float acc = 0.f;
#pragma unroll
      for (int u = 0; u < 16; ++u) acc += pr[u] * qkvb[u * 196 + 128 + h * 16 + d];
      obuf[idx] = acc;
    }
    __syncthreads();

    // ---- proj + residual (4t per thread) ----
    {
      int j = tid & 63, tg = tid >> 6;
      float bv = bo[l * 64 + j];
      float a0 = bv, a1 = bv, a2 = bv, a3 = bv;
      const float4* ob4 = (const float4*)obuf;
#pragma unroll
      for (int c = 0; c < 16; ++c) {
        float4 w = wop[c * 64 + j];
        float4 x0 = ob4[(tg * 4 + 0) * 16 + c];
        float4 x1 = ob4[(tg * 4 + 1) * 16 + c];
        float4 x2 = ob4[(tg * 4 + 2) * 16 + c];
        float4 x3 = ob4[(tg * 4 + 3) * 16 + c];
        a0 += w.x * x0.x + w.y * x0.y + w.z * x0.z + w.w * x0.w;
        a1 += w.x * x1.x + w.y * x1.y + w.z * x1.z + w.w * x1.w;
        a2 += w.x * x2.x + w.y * x2.y + w.z * x2.z + w.w * x2.w;
        a3 += w.x * x3.x + w.y * x3.y + w.z * x3.z + w.w * x3.w;
      }
      tmpb[(tg * 4 + 0) * 64 + j] = xbuf[(tg * 4 + 0) * 64 + j] + a0;
      tmpb[(tg * 4 + 1) * 64 + j] = xbuf[(tg * 4 + 1) * 64 + j] + a1;
      tmpb[(tg * 4 + 2) * 64 + j] = xbuf[(tg * 4 + 2) * 64 + j] + a2;
      tmpb[(tg * 4 + 3) * 64 + j] = xbuf[(tg * 4 + 3) * 64 + j] + a3;
    }
    __syncthreads();

    // ---- LN1 (16 lanes per token) ----
    {
      int t = tid >> 4, i2 = tid & 15;
      float4 v = ((const float4*)(tmpb + t * 64))[i2];
      float s = v.x + v.y + v.z + v.w;
      s += __shfl_xor(s, 1); s += __shfl_xor(s, 2);
      s += __shfl_xor(s, 4); s += __shfl_xor(s, 8);
      float mu = s * (1.f / 64.f);
      float d0 = v.x - mu, d1 = v.y - mu, d2 = v.z - mu, d3 = v.w - mu;
      float vr = d0 * d0 + d1 * d1 + d2 * d2 + d3 * d3;
      vr += __shfl_xor(vr, 1); vr += __shfl_xor(vr, 2);
      vr += __shfl_xor(vr, 4); vr += __shfl_xor(vr, 8);
      float rs = rsqrtf(vr * (1.f / 64.f) + EPS_);
      float4 g4 = ((const float4*)(ln1g + l * 64))[i2];
      float4 b4 = ((const float4*)(ln1b + l * 64))[i2];
      float4 o4;
      o4.x = d0 * rs * g4.x + b4.x; o4.y = d1 * rs * g4.y + b4.y;
      o4.z = d2 * rs * g4.z + b4.z; o4.w = d3 * rs * g4.w + b4.w;
      ((float4*)(xbuf + t * 64))[i2] = o4;
    }
    __syncthreads();

    // ---- ff1 (relu, 4t per thread) ----
    for (int idx = tid; idx < 512; idx += 256) {
      int f = idx & 127, tg = idx >> 7;
      float bv = b1[l * 128 + f];
      float a0 = bv, a1 = bv, a2 = bv, a3 = bv;
      const float4* xb4 = (const float4*)xbuf;
#pragma unroll
      for (int c = 0; c < 16; ++c) {
        float4 w = w1p[c * 128 + f];
        float4 x0 = xb4[(tg * 4 + 0) * 16 + c];
        float4 x1 = xb4[(tg * 4 + 1) * 16 + c];
        float4 x2 = xb4[(tg * 4 + 2) * 16 + c];
        float4 x3 = xb4[(tg * 4 + 3) * 16 + c];
        a0 += w.x * x0.x + w.y * x0.y + w.z * x0.z + w.w * x0.w;
        a1 += w.x * x1.x + w.y * x1.y + w.z * x1.z + w.w * x1.w;
        a2 += w.x * x2.x + w.y * x2.y + w.z * x2.z + w.w * x2.w;
        a3 += w.x * x3.x + w.y * x3.y + w.z * x3.z + w.w * x3.w;
      }
      h1b[(tg * 4 + 0) * 132 + f] = fmaxf(a0, 0.f);
      h1b[(tg * 4 + 1) * 132 + f] = fmaxf(a1, 0.f);
      h1b[(tg * 4 + 2) * 132 + f] = fmaxf(a2, 0.f);
      h1b[(tg * 4 + 3) * 132 + f] = fmaxf(a3, 0.f);
    }
    __syncthreads();

    // ---- ff2 + residual (4t per thread) ----
    {
      int j = tid & 63, tg = tid >> 6;
      float bv = b2[l * 64 + j];
      float a0 = bv, a1 = bv, a2 = bv, a3 = bv;
#pragma unroll
      for (int c = 0; c < 32; ++c) {
        float4 w = w2p[c * 64 + j];
        float4 x0 = ((const float4*)(h1b + (tg * 4 + 0) * 132))[c];
        float4 x1 = ((const float4*)(h1b + (tg * 4 + 1) * 132))[c];
        float4 x2 = ((const float4*)(h1b + (tg * 4 + 2) * 132))[c];
        float4 x3 = ((const float4*)(h1b + (tg * 4 + 3) * 132))[c];
        a0 += w.x * x0.x + w.y * x0.y + w.z * x0.z + w.w * x0.w;
        a1 += w.x * x1.x + w.y * x1.y + w.z * x1.z + w.w * x1.w;
        a2 += w.x * x2.x + w.y * x2.y + w.z * x2.z + w.w * x2.w;
        a3 += w.x * x3.x + w.y * x3.y + w.z * x3.z + w.w * x3.w;
      }
      tmpb[(tg * 4 + 0) * 64 + j] = xbuf[(tg * 4 + 0) * 64 + j] + a0;
      tmpb[(tg * 4 + 1) * 64 + j] = xbuf[(tg * 4 + 1) * 64 + j] + a1;
      tmpb[(tg * 4 + 2) * 64 + j] = xbuf[(tg * 4 + 2) * 64 + j] + a2;
      tmpb[(tg * 4 + 3) * 64 + j] = xbuf[(tg * 4 + 3) * 64 + j] + a3;
    }
    __syncthreads();

    // ---- LN2 ----
    {
      int t = tid >> 4, i2 = tid & 15;
      float4 v = ((const float4*)(tmpb + t * 64))[i2];
      float s = v.x + v.y + v.z + v.w;
      s += __shfl_xor(s, 1); s += __shfl_xor(s, 2);
      s += __shfl_xor(s, 4); s += __shfl_xor(s, 8);
      float mu = s * (1.f / 64.f);
      float d0 = v.x - mu, d1 = v.y - mu, d2 = v.z - mu, d3 = v.w - mu;
      float vr = d0 * d0 + d1 * d1 + d2 * d2 + d3 * d3;
      vr += __shfl_xor(vr, 1); vr += __shfl_xor(vr, 2);
      vr += __shfl_xor(vr, 4); vr += __shfl_xor(vr, 8);
      float rs = rsqrtf(vr * (1.f / 64.f) + EPS_);
      float4 g4 = ((const float4*)(ln2g + l * 64))[i2];
      float4 b4 = ((const float4*)(ln2b + l * 64))[i2];
      float4 o4;
      o4.x = d0 * rs * g4.x + b4.x; o4.y = d1 * rs * g4.y + b4.y;
      o4.z = d2 * rs * g4.z + b4.z; o4.w = d3 * rs * g4.w + b4.w;
      ((float4*)(xbuf + t * 64))[i2] = o4;
    }
    __syncthreads();
  }

  if (tid < NC_) {
    float acc = clfb[tid];
    const float* wr = &clfw[tid * DM_];
    for (int d = 0; d < DM_; ++d) acc += xbuf[d] * wr[d];
    out[b * NC_ + tid] = acc;
  }
}

extern "C" void kernel_launch(void* const* d_in, const int* in_sizes, int n_in,
                              void* d_out, int out_size, void* d_ws, size_t ws_size,
                              hipStream_t stream) {
  (void)in_sizes; (void)n_in; (void)out_size; (void)ws_size;
  const float* X    = (const float*)d_in[0];
  const float* A    = (const float*)d_in[1];
  const float* c1w  = (const float*)d_in[2];
  const float* c1b  = (const float*)d_in[3];
  const float* c2w  = (const float*)d_in[4];
  const float* c2b  = (const float*)d_in[5];
  const float* g1W  = (const float*)d_in[6];
  const float* g1q  = (const float*)d_in[7];
  const float* g1g  = (const float*)d_in[8];
  const float* g1b  = (const float*)d_in[9];
  const float* g1m  = (const float*)d_in[10];
  const float* g1v  = (const float*)d_in[11];
  const float* g2W  = (const float*)d_in[12];
  const float* g2q  = (const float*)d_in[13];
  const float* g2g  = (const float*)d_in[14];
  const float* g2b  = (const float*)d_in[15];
  const float* g2m  = (const float*)d_in[16];
  const float* g2v  = (const float*)d_in[17];
  const float* cls  = (const float*)d_in[18];
  const float* pos  = (const float*)d_in[19];
  const float* wqkv = (const float*)d_in[20];
  const float* bqkv = (const float*)d_in[21];
  const float* wo   = (const float*)d_in[22];
  const float* bo   = (const float*)d_in[23];
  const float* ln1g = (const float*)d_in[24];
  const float* ln1b = (const float*)d_in[25];
  const float* w1   = (const float*)d_in[26];
  const float* b1   = (const float*)d_in[27];
  const float* w2   = (const float*)d_in[28];
  const float* b2   = (const float*)d_in[29];
  const float* ln2g = (const float*)d_in[30];
  const float* ln2b = (const float*)d_in[31];
  const float* clfw = (const float*)d_in[32];
  const float* clfb = (const float*)d_in[33];
  float* out = (float*)d_out;

  // ---- workspace layout (bytes) ----
  char* wsb = (char*)d_ws;
  ushort_t* BmatT = (ushort_t*)(wsb + 0);                  //  37888
  float* Wq4  = (float*)(wsb + 37888);                     // 196608
  float* Wo4  = (float*)(wsb + 234496);                    //  65536
  float* W14  = (float*)(wsb + 300032);                    // 131072
  float* W24  = (float*)(wsb + 431104);                    // 131072
  float* Xf   = (float*)(wsb + 562176);                    // 4669440
  ushort_t* W1h = (ushort_t*)(wsb + 5231616);              //  16384
  ushort_t* W1l = (ushort_t*)(wsb + 5248000);              //  16384
  ushort_t* W2h = (ushort_t*)(wsb + 5264384);              //  16384
  ushort_t* W2l = (ushort_t*)(wsb + 5280768);              //  16384
  float* G    = (float*)(wsb + 5297152);                   //  245760

  k_prep<<<650, 256, 0, stream>>>(c2w, wqkv, wo, w1, w2, g1W, g2W,
                                  BmatT, Wq4, Wo4, W14, W24,
                                  W1h, W1l, W2h, W2l);
  k_temporal<<<B_ * SEG_ * N_ / RPB, 256, 0, stream>>>(
      X, c1w, c1b, c2b, BmatT, Xf);
  k_gcn<<<B_ * SEG_, 256, 0, stream>>>(A, Xf, W1h, W1l, W2h, W2l,
                                       g1q, g2q, g1g, g1b, g1m, g1v,
                                       g2g, g2b, g2m, g2v, G);
  k_transformer<<<B_, 256, 0, stream>>>(G, cls, pos,
                                        (const float4*)Wq4, (const float4*)Wo4,
                                        (const float4*)W14, (const float4*)W24,
                                        bqkv, bo, ln1g, ln1b, b1, b2, ln2g, ln2b,
                                        clfw, clfb, out);
}

// Round 4
// 253.377 us; speedup vs baseline: 3.0158x; 1.1472x over previous
//
#include <hip/hip_runtime.h>
#include <cmath>

#define B_ 64
#define N_ 19
#define SEG_ 15
#define T_ 400
#define FIN_ 64
#define HID_ 128
#define K_ 4
#define NH_ 4
#define DM_ 64
#define FF_ 128
#define L_ 4
#define NC_ 3
#define EPS_ 1e-5f

typedef __attribute__((ext_vector_type(8))) short bf16x8;
typedef __attribute__((ext_vector_type(4))) float f32x4;
typedef unsigned short ushort_t;

__device__ __forceinline__ ushort_t f2bf(float x) {
  union { float f; unsigned u; } a; a.f = x;
  unsigned r = a.u + 0x7fffu + ((a.u >> 16) & 1u);
  return (ushort_t)(r >> 16);
}
__device__ __forceinline__ float bf2f(ushort_t h) {
  union { unsigned u; float f; } a; a.u = ((unsigned)h) << 16;
  return a.f;
}

// ================= k_prep =================
// BmatT (conv2 B, bf16), transformer weights hi/lo bf16 (per-layer block:
// qkv@0, wo@12288, w1@16384, w2@24576 within l*32768), GCN weight splits.
__global__ __launch_bounds__(256) void k_prep(
    const float* __restrict__ c2w,
    const float* __restrict__ wqkv, const float* __restrict__ wo,
    const float* __restrict__ w1, const float* __restrict__ w2,
    const float* __restrict__ g1W, const float* __restrict__ g2W,
    ushort_t* __restrict__ bt,
    ushort_t* __restrict__ Th, ushort_t* __restrict__ Tl,
    ushort_t* __restrict__ W1h, ushort_t* __restrict__ W1l,
    ushort_t* __restrict__ W2h, ushort_t* __restrict__ W2l) {
  int gid = blockIdx.x * 256 + threadIdx.x;
  if (gid < 18944) {                       // BmatT[oc][kk*32+ic] = c2w[oc][ic][kk]
    int oc = gid / 296, k = gid - oc * 296;
    int ic = k & 31, kk = k >> 5;
    ushort_t v = 0;
    if (kk < 9) v = f2bf(c2w[oc * 288 + ic * 9 + kk]);
    bt[gid] = v;
  } else if (gid < 68096) {                // wqkv: L x 192 x 64
    int i = gid - 18944;
    int l = i / 12288, r = i % 12288;
    float v = wqkv[i];
    ushort_t h = f2bf(v);
    int dst = l * 32768 + r;
    Th[dst] = h; Tl[dst] = f2bf(v - bf2f(h));
  } else if (gid < 84480) {                // wo: L x 64 x 64
    int i = gid - 68096;
    int l = i / 4096, r = i % 4096;
    float v = wo[i];
    ushort_t h = f2bf(v);
    int dst = l * 32768 + 12288 + r;
    Th[dst] = h; Tl[dst] = f2bf(v - bf2f(h));
  } else if (gid < 117248) {               // w1: L x 128 x 64
    int i = gid - 84480;
    int l = i / 8192, r = i % 8192;
    float v = w1[i];
    ushort_t h = f2bf(v);
    int dst = l * 32768 + 16384 + r;
    Th[dst] = h; Tl[dst] = f2bf(v - bf2f(h));
  } else if (gid < 150016) {               // w2: L x 64 x 128
    int i = gid - 117248;
    int l = i / 8192, r = i % 8192;
    float v = w2[i];
    ushort_t h = f2bf(v);
    int dst = l * 32768 + 24576 + r;
    Th[dst] = h; Tl[dst] = f2bf(v - bf2f(h));
  } else if (gid < 158208) {               // g1_W split hi/lo [128][64]
    int i = gid - 150016;
    float v = g1W[i];
    ushort_t h = f2bf(v);
    W1h[i] = h;
    W1l[i] = f2bf(v - bf2f(h));
  } else if (gid < 166400) {               // g2_W split hi/lo [64][128]
    int i = gid - 158208;
    float v = g2W[i];
    ushort_t h = f2bf(v);
    W2h[i] = h;
    W2l[i] = f2bf(v - bf2f(h));
  }
}

// ================= Kernel 1: temporal encoder (unchanged from R3) =========
#define RPB 4
#define ICP 40
#define P1R 40
#define OFFB_XP 0
#define OFFB_W1 6784
#define OFFB_P1 9984
#define SMEM_T 22784

__global__ __launch_bounds__(256, 4) void k_temporal(
    const float* __restrict__ X, const float* __restrict__ c1w,
    const float* __restrict__ c1b, const float* __restrict__ c2b,
    const ushort_t* __restrict__ BmatT, float* __restrict__ Xf) {
  __shared__ __align__(16) unsigned char smem[SMEM_T];
  float* xp  = (float*)(smem + OFFB_XP);                   // [4][424]
  float* w1s = (float*)(smem + OFFB_W1);                   // [800]
  ushort_t* p1T = (ushort_t*)(smem + OFFB_P1);             // [4*40][40]
  float* Dbuf = (float*)(smem + OFFB_XP);                  // overlay [64][66]

  const int tid = threadIdx.x;
  const int row0 = blockIdx.x * RPB;

  for (int i = tid; i < 800; i += 256) w1s[i] = c1w[i];
  for (int i = tid; i < RPB * P1R * ICP / 2; i += 256) ((unsigned*)p1T)[i] = 0u;
  for (int r = 0; r < RPB; ++r) {
    const int gr = row0 + r;
    const int n = gr % N_;
    const int s = (gr / N_) % SEG_;
    const int b = gr / (N_ * SEG_);
    const float* xin = X + (((size_t)b * N_ + n) * SEG_ + s) * T_;
    for (int i = tid; i < 424; i += 256) {
      int t = i - 12;
      xp[r * 424 + i] = (t >= 0 && t < T_) ? xin[t] : 0.f;
    }
  }
  __syncthreads();

  {
    const int oc = tid & 31, sub = tid >> 5;
    float wr[25];
#pragma unroll
    for (int k = 0; k < 25; ++k) wr[k] = w1s[oc * 25 + k];
    const float bias = c1b[oc];
    for (int r = 0; r < RPB; ++r) {
      const float* xb = xp + r * 424;
      for (int j = sub; j < 25; j += 8) {
        float xr[37];
#pragma unroll
        for (int k = 0; k < 37; ++k) xr[k] = xb[16 * j + k];
        float m = -1e30f;
#pragma unroll
        for (int p = 0; p < 4; ++p) {
          float acc = bias;
#pragma unroll
          for (int k = 0; k < 25; ++k) acc += xr[4 * p + k] * wr[k];
          m = fmaxf(m, acc);
        }
        p1T[(r * P1R + j + 4) * ICP + oc] = f2bf(fmaxf(m, 0.f));
      }
    }
  }
  __syncthreads();

  const int lane = tid & 63, wv = tid >> 6;
  const int quad = lane >> 4, nl = lane & 15;
  f32x4 acc[4];
  int abase[4];
#pragma unroll
  for (int tm = 0; tm < 4; ++tm) {
    acc[tm] = (f32x4){0.f, 0.f, 0.f, 0.f};
    int m = tm * 16 + nl;
    int rl = m / 14;
    int op = m - rl * 14;
    if (rl > 3) rl = 3;
    if (op > 13) op = 13;
    abase[tm] = (rl * P1R + 2 * op) * ICP + quad * 8;
  }
  const ushort_t* brow = BmatT + (wv * 16 + nl) * 296 + quad * 8;
#pragma unroll
  for (int kk = 0; kk < 9; ++kk) {
    bf16x8 bfr = *(const bf16x8*)(brow + kk * 32);
#pragma unroll
    for (int tm = 0; tm < 4; ++tm) {
      bf16x8 afr = *(const bf16x8*)(p1T + abase[tm] + kk * ICP);
      acc[tm] = __builtin_amdgcn_mfma_f32_16x16x32_bf16(afr, bfr, acc[tm], 0, 0, 0);
    }
  }
  __syncthreads();

#pragma unroll
  for (int tm = 0; tm < 4; ++tm)
#pragma unroll
    for (int rg = 0; rg < 4; ++rg)
      Dbuf[(tm * 16 + quad * 4 + rg) * 66 + wv * 16 + nl] = acc[tm][rg];
  __syncthreads();

  for (int o = tid; o < RPB * 64; o += 256) {
    int rl = o >> 6, oc = o & 63;
    float bias = c2b[oc];
    const float* dr = Dbuf + (rl * 14) * 66 + oc;
    float s = 0.f;
#pragma unroll
    for (int jj = 0; jj < 6; ++jj) {
      float v = fmaxf(dr[(2 * jj) * 66], dr[(2 * jj + 1) * 66]) + bias;
      s += fmaxf(v, 0.f);
    }
    Xf[(size_t)(row0 + rl) * FIN_ + oc] = s * (1.f / 6.f);
  }
}

// ================= Kernel 2: fused GCN (unchanged from R3) =================
__global__ __launch_bounds__(256) void k_gcn(
    const float* __restrict__ A, const float* __restrict__ Xf,
    const ushort_t* __restrict__ W1h, const ushort_t* __restrict__ W1l,
    const ushort_t* __restrict__ W2h, const ushort_t* __restrict__ W2l,
    const float* __restrict__ q1, const float* __restrict__ q2,
    const float* __restrict__ b1g, const float* __restrict__ b1b,
    const float* __restrict__ b1m, const float* __restrict__ b1v,
    const float* __restrict__ b2g, const float* __restrict__ b2b,
    const float* __restrict__ b2m, const float* __restrict__ b2v,
    float* __restrict__ G) {
  const int bs = blockIdx.x;
  const int b = bs / SEG_;
  const int s = bs % SEG_;
  const int tid = threadIdx.x;

  __shared__ __align__(16) ushort_t xh[32 * 72], xl[32 * 72];
  __shared__ __align__(16) ushort_t Hh[32 * 136], Hl[32 * 136];
  __shared__ float abar1[N_ * N_], abar2[N_ * N_];
  __shared__ float ybuf[N_ * 130];
  __shared__ float zbuf[N_ * 64];
  __shared__ float sc1[HID_], sh1[HID_], sc2[FIN_], sh2[FIN_];

  {
    float p0 = q1[0], p1 = q1[1], p2 = q1[2], p3 = q1[3];
    float mx = fmaxf(fmaxf(p0, p1), fmaxf(p2, p3));
    float e0 = expf(p0 - mx), e1 = expf(p1 - mx), e2 = expf(p2 - mx), e3 = expf(p3 - mx);
    float inv = 1.f / (e0 + e1 + e2 + e3);
    float a0 = e0 * inv, a1 = e1 * inv, a2 = e2 * inv, a3 = e3 * inv;
    float r0 = q2[0], r1 = q2[1], r2 = q2[2], r3 = q2[3];
    float mx2 = fmaxf(fmaxf(r0, r1), fmaxf(r2, r3));
    float f0 = expf(r0 - mx2), f1 = expf(r1 - mx2), f2 = expf(r2 - mx2), f3 = expf(r3 - mx2);
    float inv2 = 1.f / (f0 + f1 + f2 + f3);
    float c0 = f0 * inv2, c1 = f1 * inv2, c2 = f2 * inv2, c3 = f3 * inv2;
    const size_t kstride = (size_t)SEG_ * N_ * N_;
    const float* Ab = A + ((size_t)b * K_ * SEG_ + s) * (N_ * N_);
    for (int i = tid; i < N_ * N_; i += 256) {
      float v0 = Ab[i], v1 = Ab[i + kstride], v2 = Ab[i + 2 * kstride], v3 = Ab[i + 3 * kstride];
      abar1[i] = a0 * v0 + a1 * v1 + a2 * v2 + a3 * v3;
      abar2[i] = c0 * v0 + c1 * v1 + c2 * v2 + c3 * v3;
    }
  }

  for (int i = tid; i < 32 * 72 / 2; i += 256) {
    ((unsigned*)xh)[i] = 0u; ((unsigned*)xl)[i] = 0u;
  }
  for (int i = tid; i < 32 * 136 / 2; i += 256) {
    ((unsigned*)Hh)[i] = 0u; ((unsigned*)Hl)[i] = 0u;
  }
  for (int o = tid; o < HID_; o += 256) {
    float sc = b1g[o] * rsqrtf(b1v[o] + EPS_);
    sc1[o] = sc; sh1[o] = b1b[o] - b1m[o] * sc;
  }
  for (int o = tid; o < FIN_; o += 256) {
    float sc = b2g[o] * rsqrtf(b2v[o] + EPS_);
    sc2[o] = sc; sh2[o] = b2b[o] - b2m[o] * sc;
  }
  __syncthreads();

  const float* xb = Xf + (size_t)bs * N_ * FIN_;
  for (int i = tid; i < N_ * FIN_; i += 256) {
    int r = i >> 6, f = i & 63;
    float v = xb[i];
    ushort_t h = f2bf(v);
    xh[r * 72 + f] = h;
    xl[r * 72 + f] = f2bf(v - bf2f(h));
  }
  __syncthreads();

  const int lane = tid & 63, wv = tid >> 6;
  const int quad = lane >> 4, nl = lane & 15;

#pragma unroll
  for (int mt = 0; mt < 2; ++mt) {
#pragma unroll
    for (int ntl = 0; ntl < 2; ++ntl) {
      const int nt = wv * 2 + ntl;
      f32x4 acc = (f32x4){0.f, 0.f, 0.f, 0.f};
#pragma unroll
      for (int ks = 0; ks < 2; ++ks) {
        bf16x8 ah = *(const bf16x8*)(xh + (mt * 16 + nl) * 72 + ks * 32 + quad * 8);
        bf16x8 al = *(const bf16x8*)(xl + (mt * 16 + nl) * 72 + ks * 32 + quad * 8);
        bf16x8 bh = *(const bf16x8*)(W1h + (nt * 16 + nl) * 64 + ks * 32 + quad * 8);
        bf16x8 bl = *(const bf16x8*)(W1l + (nt * 16 + nl) * 64 + ks * 32 + quad * 8);
        acc = __builtin_amdgcn_mfma_f32_16x16x32_bf16(ah, bh, acc, 0, 0, 0);
        acc = __builtin_amdgcn_mfma_f32_16x16x32_bf16(al, bh, acc, 0, 0, 0);
        acc = __builtin_amdgcn_mfma_f32_16x16x32_bf16(ah, bl, acc, 0, 0, 0);
      }
#pragma unroll
      for (int r = 0; r < 4; ++r) {
        int m = mt * 16 + quad * 4 + r;
        if (m < N_) ybuf[m * 130 + nt * 16 + nl] = acc[r];
      }
    }
  }
  __syncthreads();

  for (int idx = tid; idx < N_ * HID_; idx += 256) {
    int nn = idx >> 7, o = idx & 127;
    float acc = 0.f;
    const float* ar = &abar1[nn * N_];
#pragma unroll
    for (int m = 0; m < N_; ++m) acc += ar[m] * ybuf[m * 130 + o];
    float h = fmaxf(acc * sc1[o] + sh1[o], 0.f);
    ushort_t hh = f2bf(h);
    Hh[nn * 136 + o] = hh;
    Hl[nn * 136 + o] = f2bf(h - bf2f(hh));
  }
  __syncthreads();

  {
    const int nt = wv;
#pragma unroll
    for (int mt = 0; mt < 2; ++mt) {
      f32x4 acc = (f32x4){0.f, 0.f, 0.f, 0.f};
#pragma unroll
      for (int ks = 0; ks < 4; ++ks) {
        bf16x8 ah = *(const bf16x8*)(Hh + (mt * 16 + nl) * 136 + ks * 32 + quad * 8);
        bf16x8 al = *(const bf16x8*)(Hl + (mt * 16 + nl) * 136 + ks * 32 + quad * 8);
        bf16x8 bh = *(const bf16x8*)(W2h + (nt * 16 + nl) * 128 + ks * 32 + quad * 8);
        bf16x8 bl = *(const bf16x8*)(W2l + (nt * 16 + nl) * 128 + ks * 32 + quad * 8);
        acc = __builtin_amdgcn_mfma_f32_16x16x32_bf16(ah, bh, acc, 0, 0, 0);
        acc = __builtin_amdgcn_mfma_f32_16x16x32_bf16(al, bh, acc, 0, 0, 0);
        acc = __builtin_amdgcn_mfma_f32_16x16x32_bf16(ah, bl, acc, 0, 0, 0);
      }
#pragma unroll
      for (int r = 0; r < 4; ++r) {
        int m = mt * 16 + quad * 4 + r;
        if (m < N_) ybuf[m * 66 + nt * 16 + nl] = acc[r];
      }
    }
  }
  __syncthreads();

  for (int idx = tid; idx < N_ * FIN_; idx += 256) {
    int nn = idx >> 6, o = idx & 63;
    float acc = 0.f;
    const float* ar = &abar2[nn * N_];
#pragma unroll
    for (int m = 0; m < N_; ++m) acc += ar[m] * ybuf[m * 66 + o];
    zbuf[idx] = fmaxf(acc * sc2[o] + sh2[o], 0.f);
  }
  __syncthreads();

  if (tid < FIN_) {
    float ssum = 0.f;
#pragma unroll
    for (int nn = 0; nn < N_; ++nn) ssum += zbuf[nn * 64 + tid];
    G[(size_t)bs * FIN_ + tid] = ssum * (1.f / (float)N_);
  }
}

// ================= Kernel 3: transformer (MFMA) + classifier =============
// Weight GEMMs via bf16x3 MFMA; B-frags straight from L2-resident hi/lo
// weights in native [n][k] layout. A-frags in LDS (strides 72/136: 2-way
// bank aliasing = free). Attention/LN stay fp32 VALU.
__global__ __launch_bounds__(256) void k_transformer(
    const float* __restrict__ G, const float* __restrict__ cls,
    const float* __restrict__ pos,
    const ushort_t* __restrict__ Th, const ushort_t* __restrict__ Tl,
    const float* __restrict__ bqkv, const float* __restrict__ bo,
    const float* __restrict__ ln1g, const float* __restrict__ ln1b,
    const float* __restrict__ b1, const float* __restrict__ b2,
    const float* __restrict__ ln2g, const float* __restrict__ ln2b,
    const float* __restrict__ clfw, const float* __restrict__ clfb,
    float* __restrict__ out) {
  const int b = blockIdx.x;
  const int tid = threadIdx.x;
  const int lane = tid & 63, wv = tid >> 6;
  const int quad = lane >> 4, nl = lane & 15;

  __shared__ float xbuf[16 * 64];
  __shared__ __align__(16) ushort_t xh[16 * 72], xl[16 * 72];
  __shared__ float qkvb[16 * 196];
  __shared__ float scb[NH_ * 16 * 16];
  __shared__ __align__(16) ushort_t oh[16 * 72], ol[16 * 72];
  __shared__ __align__(16) ushort_t h1h[16 * 136], h1l[16 * 136];
  __shared__ float tmpb[16 * 64];

  for (int i = tid; i < 16 * 64; i += 256) {
    int t = i >> 6, d = i & 63;
    float base = (t == 0) ? cls[d] : G[((size_t)b * SEG_ + (t - 1)) * DM_ + d];
    float v = base + pos[t * DM_ + d];
    xbuf[i] = v;
    ushort_t h = f2bf(v);
    xh[t * 72 + d] = h;
    xl[t * 72 + d] = f2bf(v - bf2f(h));
  }
  __syncthreads();

  for (int l = 0; l < L_; ++l) {
    const ushort_t* TH = Th + l * 32768;
    const ushort_t* TL = Tl + l * 32768;

    // ---- qkv: [16x192] = X[16x64] @ Wqkv^T, MFMA ----
#pragma unroll
    for (int ntl = 0; ntl < 3; ++ntl) {
      const int nt = wv * 3 + ntl;
      f32x4 acc = (f32x4){0.f, 0.f, 0.f, 0.f};
#pragma unroll
      for (int ks = 0; ks < 2; ++ks) {
        bf16x8 ah = *(const bf16x8*)(xh + nl * 72 + ks * 32 + quad * 8);
        bf16x8 al = *(const bf16x8*)(xl + nl * 72 + ks * 32 + quad * 8);
        bf16x8 bh = *(const bf16x8*)(TH + (nt * 16 + nl) * 64 + ks * 32 + quad * 8);
        bf16x8 bl = *(const bf16x8*)(TL + (nt * 16 + nl) * 64 + ks * 32 + quad * 8);
        acc = __builtin_amdgcn_mfma_f32_16x16x32_bf16(ah, bh, acc, 0, 0, 0);
        acc = __builtin_amdgcn_mfma_f32_16x16x32_bf16(al, bh, acc, 0, 0, 0);
        acc = __builtin_amdgcn_mfma_f32_16x16x32_bf16(ah, bl, acc, 0, 0, 0);
      }
      const int j = nt * 16 + nl;
      const float bias = bqkv[l * 192 + j];
#pragma unroll
      for (int r = 0; r < 4; ++r)
        qkvb[(quad * 4 + r) * 196 + j] = acc[r] + bias;
    }
    __syncthreads();

    // ---- scores ----
    for (int idx = tid; idx < 1024; idx += 256) {
      int h = idx >> 8, t = (idx >> 4) & 15, u = idx & 15;
      const float* qr = &qkvb[t * 196 + h * 16];
      const float* kr = &qkvb[u * 196 + 64 + h * 16];
      float acc = 0.f;
#pragma unroll
      for (int d = 0; d < 16; ++d) acc += qr[d] * kr[d];
      scb[idx] = acc * 0.25f;
    }
    __syncthreads();

    // ---- softmax (4 lanes per row) ----
    {
      int row = tid >> 2, qq = tid & 3;
      float* r = &scb[row * 16 + qq * 4];
      float v0 = r[0], v1 = r[1], v2 = r[2], v3 = r[3];
      float mxv = fmaxf(fmaxf(v0, v1), fmaxf(v2, v3));
      mxv = fmaxf(mxv, __shfl_xor(mxv, 1));
      mxv = fmaxf(mxv, __shfl_xor(mxv, 2));
      v0 = expf(v0 - mxv); v1 = expf(v1 - mxv);
      v2 = expf(v2 - mxv); v3 = expf(v3 - mxv);
      float sum = v0 + v1 + v2 + v3;
      sum += __shfl_xor(sum, 1);
      sum += __shfl_xor(sum, 2);
      float is = 1.f / sum;
      r[0] = v0 * is; r[1] = v1 * is; r[2] = v2 * is; r[3] = v3 * is;
    }
    __syncthreads();

    // ---- o = attn @ v -> oh/ol (bf16 hi/lo A-operand) ----
    for (int idx = tid; idx < 1024; idx += 256) {
      int t = idx >> 6, e = idx & 63, h = e >> 4, d = e & 15;
      const float* pr = &scb[(h * 16 + t) * 16];
      float acc = 0.f;
#pragma unroll
      for (int u = 0; u < 16; ++u) acc += pr[u] * qkvb[u * 196 + 128 + h * 16 + d];
      ushort_t hh = f2bf(acc);
      oh[t * 72 + e] = hh;
      ol[t * 72 + e] = f2bf(acc - bf2f(hh));
    }
    __syncthreads();

    // ---- proj: [16x64] = O @ Wo^T, MFMA; + residual ----
    {
      const int nt = wv;
      f32x4 acc = (f32x4){0.f, 0.f, 0.f, 0.f};
#pragma unroll
      for (int ks = 0; ks < 2; ++ks) {
        bf16x8 ah = *(const bf16x8*)(oh + nl * 72 + ks * 32 + quad * 8);
        bf16x8 al = *(const bf16x8*)(ol + nl * 72 + ks * 32 + quad * 8);
        bf16x8 bh = *(const bf16x8*)(TH + 12288 + (nt * 16 + nl) * 64 + ks * 32 + quad * 8);
        bf16x8 bl = *(const bf16x8*)(TL + 12288 + (nt * 16 + nl) * 64 + ks * 32 + quad * 8);
        acc = __builtin_amdgcn_mfma_f32_16x16x32_bf16(ah, bh, acc, 0, 0, 0);
        acc = __builtin_amdgcn_mfma_f32_16x16x32_bf16(al, bh, acc, 0, 0, 0);
        acc = __builtin_amdgcn_mfma_f32_16x16x32_bf16(ah, bl, acc, 0, 0, 0);
      }
      const int d = nt * 16 + nl;
      const float bias = bo[l * 64 + d];
#pragma unroll
      for (int r = 0; r < 4; ++r) {
        int t = quad * 4 + r;
        tmpb[t * 64 + d] = xbuf[t * 64 + d] + acc[r] + bias;
      }
    }
    __syncthreads();

    // ---- LN1 (16 lanes per token) -> xbuf fp32 + xh/xl bf16 ----
    {
      int t = tid >> 4, i2 = tid & 15;
      float4 v = ((const float4*)(tmpb + t * 64))[i2];
      float s = v.x + v.y + v.z + v.w;
      s += __shfl_xor(s, 1); s += __shfl_xor(s, 2);
      s += __shfl_xor(s, 4); s += __shfl_xor(s, 8);
      float mu = s * (1.f / 64.f);
      float d0 = v.x - mu, d1 = v.y - mu, d2 = v.z - mu, d3 = v.w - mu;
      float vr = d0 * d0 + d1 * d1 + d2 * d2 + d3 * d3;
      vr += __shfl_xor(vr, 1); vr += __shfl_xor(vr, 2);
      vr += __shfl_xor(vr, 4); vr += __shfl_xor(vr, 8);
      float rs = rsqrtf(vr * (1.f / 64.f) + EPS_);
      float4 g4 = ((const float4*)(ln1g + l * 64))[i2];
      float4 b4 = ((const float4*)(ln1b + l * 64))[i2];
      float4 o4;
      o4.x = d0 * rs * g4.x + b4.x; o4.y = d1 * rs * g4.y + b4.y;
      o4.z = d2 * rs * g4.z + b4.z; o4.w = d3 * rs * g4.w + b4.w;
      ((float4*)(xbuf + t * 64))[i2] = o4;
      int base = t * 72 + i2 * 4;
      ushort_t h0 = f2bf(o4.x), h1 = f2bf(o4.y), h2 = f2bf(o4.z), h3 = f2bf(o4.w);
      xh[base + 0] = h0; xh[base + 1] = h1; xh[base + 2] = h2; xh[base + 3] = h3;
      xl[base + 0] = f2bf(o4.x - bf2f(h0));
      xl[base + 1] = f2bf(o4.y - bf2f(h1));
      xl[base + 2] = f2bf(o4.z - bf2f(h2));
      xl[base + 3] = f2bf(o4.w - bf2f(h3));
    }
    __syncthreads();

    // ---- ff1: [16x128] = X @ W1^T, MFMA; relu -> h1h/h1l ----
#pragma unroll
    for (int ntl = 0; ntl < 2; ++ntl) {
      const int nt = wv * 2 + ntl;
      f32x4 acc = (f32x4){0.f, 0.f, 0.f, 0.f};
#pragma unroll
      for (int ks = 0; ks < 2; ++ks) {
        bf16x8 ah = *(const bf16x8*)(xh + nl * 72 + ks * 32 + quad * 8);
        bf16x8 al = *(const bf16x8*)(xl + nl * 72 + ks * 32 + quad * 8);
        bf16x8 bh = *(const bf16x8*)(TH + 16384 + (nt * 16 + nl) * 64 + ks * 32 + quad * 8);
        bf16x8 bl = *(const bf16x8*)(TL + 16384 + (nt * 16 + nl) * 64 + ks * 32 + quad * 8);
        acc = __builtin_amdgcn_mfma_f32_16x16x32_bf16(ah, bh, acc, 0, 0, 0);
        acc = __builtin_amdgcn_mfma_f32_16x16x32_bf16(al, bh, acc, 0, 0, 0);
        acc = __builtin_amdgcn_mfma_f32_16x16x32_bf16(ah, bl, acc, 0, 0, 0);
      }
      const int f = nt * 16 + nl;
      const float bias = b1[l * 128 + f];
#pragma unroll
      for (int r = 0; r < 4; ++r) {
        int t = quad * 4 + r;
        float v = fmaxf(acc[r] + bias, 0.f);
        ushort_t hh = f2bf(v);
        h1h[t * 136 + f] = hh;
        h1l[t * 136 + f] = f2bf(v - bf2f(hh));
      }
    }
    __syncthreads();

    // ---- ff2: [16x64] = H1 @ W2^T, MFMA; + residual ----
    {
      const int nt = wv;
      f32x4 acc = (f32x4){0.f, 0.f, 0.f, 0.f};
#pragma unroll
      for (int ks = 0; ks < 4; ++ks) {
        bf16x8 ah = *(const bf16x8*)(h1h + nl * 136 + ks * 32 + quad * 8);
        bf16x8 al = *(const bf16x8*)(h1l + nl * 136 + ks * 32 + quad * 8);
        bf16x8 bh = *(const bf16x8*)(TH + 24576 + (nt * 16 + nl) * 128 + ks * 32 + quad * 8);
        bf16x8 bl = *(const bf16x8*)(TL + 24576 + (nt * 16 + nl) * 128 + ks * 32 + quad * 8);
        acc = __builtin_amdgcn_mfma_f32_16x16x32_bf16(ah, bh, acc, 0, 0, 0);
        acc = __builtin_amdgcn_mfma_f32_16x16x32_bf16(al, bh, acc, 0, 0, 0);
        acc = __builtin_amdgcn_mfma_f32_16x16x32_bf16(ah, bl, acc, 0, 0, 0);
      }
      const int d = nt * 16 + nl;
      const float bias = b2[l * 64 + d];
#pragma unroll
      for (int r = 0; r < 4; ++r) {
        int t = quad * 4 + r;
        tmpb[t * 64 + d] = xbuf[t * 64 + d] + acc[r] + bias;
      }
    }
    __syncthreads();

    // ---- LN2 -> xbuf + xh/xl ----
    {
      int t = tid >> 4, i2 = tid & 15;
      float4 v = ((const float4*)(tmpb + t * 64))[i2];
      float s = v.x + v.y + v.z + v.w;
      s += __shfl_xor(s, 1); s += __shfl_xor(s, 2);
      s += __shfl_xor(s, 4); s += __shfl_xor(s, 8);
      float mu = s * (1.f / 64.f);
      float d0 = v.x - mu, d1 = v.y - mu, d2 = v.z - mu, d3 = v.w - mu;
      float vr = d0 * d0 + d1 * d1 + d2 * d2 + d3 * d3;
      vr += __shfl_xor(vr, 1); vr += __shfl_xor(vr, 2);
      vr += __shfl_xor(vr, 4); vr += __shfl_xor(vr, 8);
      float rs = rsqrtf(vr * (1.f / 64.f) + EPS_);
      float4 g4 = ((const float4*)(ln2g + l * 64))[i2];
      float4 b4 = ((const float4*)(ln2b + l * 64))[i2];
      float4 o4;
      o4.x = d0 * rs * g4.x + b4.x; o4.y = d1 * rs * g4.y + b4.y;
      o4.z = d2 * rs * g4.z + b4.z; o4.w = d3 * rs * g4.w + b4.w;
      ((float4*)(xbuf + t * 64))[i2] = o4;
      int base = t * 72 + i2 * 4;
      ushort_t h0 = f2bf(o4.x), h1 = f2bf(o4.y), h2 = f2bf(o4.z), h3 = f2bf(o4.w);
      xh[base + 0] = h0; xh[base + 1] = h1; xh[base + 2] = h2; xh[base + 3] = h3;
      xl[base + 0] = f2bf(o4.x - bf2f(h0));
      xl[base + 1] = f2bf(o4.y - bf2f(h1));
      xl[base + 2] = f2bf(o4.z - bf2f(h2));
      xl[base + 3] = f2bf(o4.w - bf2f(h3));
    }
    __syncthreads();
  }

  if (tid < NC_) {
    float acc = clfb[tid];
    const float* wr = &clfw[tid * DM_];
    for (int d = 0; d < DM_; ++d) acc += xbuf[d] * wr[d];
    out[b * NC_ + tid] = acc;
  }
}

extern "C" void kernel_launch(void* const* d_in, const int* in_sizes, int n_in,
                              void* d_out, int out_size, void* d_ws, size_t ws_size,
                              hipStream_t stream) {
  (void)in_sizes; (void)n_in; (void)out_size; (void)ws_size;
  const float* X    = (const float*)d_in[0];
  const float* A    = (const float*)d_in[1];
  const float* c1w  = (const float*)d_in[2];
  const float* c1b  = (const float*)d_in[3];
  const float* c2w  = (const float*)d_in[4];
  const float* c2b  = (const float*)d_in[5];
  const float* g1W  = (const float*)d_in[6];
  const float* g1q  = (const float*)d_in[7];
  const float* g1g  = (const float*)d_in[8];
  const float* g1b  = (const float*)d_in[9];
  const float* g1m  = (const float*)d_in[10];
  const float* g1v  = (const float*)d_in[11];
  const float* g2W  = (const float*)d_in[12];
  const float* g2q  = (const float*)d_in[13];
  const float* g2g  = (const float*)d_in[14];
  const float* g2b  = (const float*)d_in[15];
  const float* g2m  = (const float*)d_in[16];
  const float* g2v  = (const float*)d_in[17];
  const float* cls  = (const float*)d_in[18];
  const float* pos  = (const float*)d_in[19];
  const float* wqkv = (const float*)d_in[20];
  const float* bqkv = (const float*)d_in[21];
  const float* wo   = (const float*)d_in[22];
  const float* bo   = (const float*)d_in[23];
  const float* ln1g = (const float*)d_in[24];
  const float* ln1b = (const float*)d_in[25];
  const float* w1   = (const float*)d_in[26];
  const float* b1   = (const float*)d_in[27];
  const float* w2   = (const float*)d_in[28];
  const float* b2   = (const float*)d_in[29];
  const float* ln2g = (const float*)d_in[30];
  const float* ln2b = (const float*)d_in[31];
  const float* clfw = (const float*)d_in[32];
  const float* clfb = (const float*)d_in[33];
  float* out = (float*)d_out;

  // ---- workspace layout (bytes) ----
  char* wsb = (char*)d_ws;
  ushort_t* BmatT = (ushort_t*)(wsb + 0);                  //  37888
  ushort_t* Th  = (ushort_t*)(wsb + 37888);                // 262144
  ushort_t* Tl  = (ushort_t*)(wsb + 300032);               // 262144
  ushort_t* W1h = (ushort_t*)(wsb + 562176);               //  16384
  ushort_t* W1l = (ushort_t*)(wsb + 578560);               //  16384
  ushort_t* W2h = (ushort_t*)(wsb + 594944);               //  16384
  ushort_t* W2l = (ushort_t*)(wsb + 611328);               //  16384
  float* Xf   = (float*)(wsb + 627712);                    // 4669440
  float* G    = (float*)(wsb + 5297152);                   //  245760 -> 5542912 total

  k_prep<<<650, 256, 0, stream>>>(c2w, wqkv, wo, w1, w2, g1W, g2W,
                                  BmatT, Th, Tl, W1h, W1l, W2h, W2l);
  k_temporal<<<B_ * SEG_ * N_ / RPB, 256, 0, stream>>>(
      X, c1w, c1b, c2b, BmatT, Xf);
  k_gcn<<<B_ * SEG_, 256, 0, stream>>>(A, Xf, W1h, W1l, W2h, W2l,
                                       g1q, g2q, g1g, g1b, g1m, g1v,
                                       g2g, g2b, g2m, g2v, G);
  k_transformer<<<B_, 256, 0, stream>>>(G, cls, pos, Th, Tl,
                                        bqkv, bo, ln1g, ln1b, b1, b2, ln2g, ln2b,
                                        clfw, clfb, out);
}

// Round 5
// 223.961 us; speedup vs baseline: 3.4119x; 1.1313x over previous
//
#include <hip/hip_runtime.h>
#include <cmath>

#define B_ 64
#define N_ 19
#define SEG_ 15
#define T_ 400
#define FIN_ 64
#define HID_ 128
#define K_ 4
#define NH_ 4
#define DM_ 64
#define FF_ 128
#define L_ 4
#define NC_ 3
#define EPS_ 1e-5f

typedef __attribute__((ext_vector_type(8))) short bf16x8;
typedef __attribute__((ext_vector_type(4))) short bf16x4;
typedef __attribute__((ext_vector_type(4))) float f32x4;
typedef unsigned short ushort_t;

__device__ __forceinline__ ushort_t f2bf(float x) {
  union { float f; unsigned u; } a; a.f = x;
  unsigned r = a.u + 0x7fffu + ((a.u >> 16) & 1u);
  return (ushort_t)(r >> 16);
}
__device__ __forceinline__ float bf2f(ushort_t h) {
  union { unsigned u; float f; } a; a.u = ((unsigned)h) << 16;
  return a.f;
}

// ================= k_prep =================
// BmatT (conv2 B bf16), transformer weights hi/lo, GCN weight splits,
// conv1 weights padded [32][32] hi/lo.
__global__ __launch_bounds__(256) void k_prep(
    const float* __restrict__ c1w, const float* __restrict__ c2w,
    const float* __restrict__ wqkv, const float* __restrict__ wo,
    const float* __restrict__ w1, const float* __restrict__ w2,
    const float* __restrict__ g1W, const float* __restrict__ g2W,
    ushort_t* __restrict__ bt,
    ushort_t* __restrict__ Th, ushort_t* __restrict__ Tl,
    ushort_t* __restrict__ W1h, ushort_t* __restrict__ W1l,
    ushort_t* __restrict__ W2h, ushort_t* __restrict__ W2l,
    ushort_t* __restrict__ C1h, ushort_t* __restrict__ C1l) {
  int gid = blockIdx.x * 256 + threadIdx.x;
  if (gid < 18944) {                       // BmatT[oc][kk*32+ic] = c2w[oc][ic][kk]
    int oc = gid / 296, k = gid - oc * 296;
    int ic = k & 31, kk = k >> 5;
    ushort_t v = 0;
    if (kk < 9) v = f2bf(c2w[oc * 288 + ic * 9 + kk]);
    bt[gid] = v;
  } else if (gid < 68096) {                // wqkv: L x 192 x 64
    int i = gid - 18944;
    int l = i / 12288, r = i % 12288;
    float v = wqkv[i];
    ushort_t h = f2bf(v);
    int dst = l * 32768 + r;
    Th[dst] = h; Tl[dst] = f2bf(v - bf2f(h));
  } else if (gid < 84480) {                // wo: L x 64 x 64
    int i = gid - 68096;
    int l = i / 4096, r = i % 4096;
    float v = wo[i];
    ushort_t h = f2bf(v);
    int dst = l * 32768 + 12288 + r;
    Th[dst] = h; Tl[dst] = f2bf(v - bf2f(h));
  } else if (gid < 117248) {               // w1: L x 128 x 64
    int i = gid - 84480;
    int l = i / 8192, r = i % 8192;
    float v = w1[i];
    ushort_t h = f2bf(v);
    int dst = l * 32768 + 16384 + r;
    Th[dst] = h; Tl[dst] = f2bf(v - bf2f(h));
  } else if (gid < 150016) {               // w2: L x 64 x 128
    int i = gid - 117248;
    int l = i / 8192, r = i % 8192;
    float v = w2[i];
    ushort_t h = f2bf(v);
    int dst = l * 32768 + 24576 + r;
    Th[dst] = h; Tl[dst] = f2bf(v - bf2f(h));
  } else if (gid < 158208) {               // g1_W split hi/lo [128][64]
    int i = gid - 150016;
    float v = g1W[i];
    ushort_t h = f2bf(v);
    W1h[i] = h;
    W1l[i] = f2bf(v - bf2f(h));
  } else if (gid < 166400) {               // g2_W split hi/lo [64][128]
    int i = gid - 158208;
    float v = g2W[i];
    ushort_t h = f2bf(v);
    W2h[i] = h;
    W2l[i] = f2bf(v - bf2f(h));
  } else if (gid < 167424) {               // conv1 w padded [32 oc][32 k] hi/lo
    int i = gid - 166400;
    int oc = i >> 5, kk = i & 31;
    float v = (kk < 25) ? c1w[oc * 25 + kk] : 0.f;
    ushort_t h = f2bf(v);
    C1h[i] = h;
    C1l[i] = f2bf(v - bf2f(h));
  }
}

// ================= Kernel 1: temporal encoder =================
// 4 rows/block. Input staged as bf16 hi/lo (padded signal). conv1 = MFMA
// GEMM over stride-4 windows (K=25 pad 32), pool4 free in C-layout regs.
// conv2 = MFMA (as R4). LDS 20.5 KB.
#define RPB 4
#define ICP 40
#define P1R 40
#define OFF_XPH 0
#define OFF_XPL 3840
#define OFF_P1  7680
#define SMEM_T  20480

__global__ __launch_bounds__(256, 4) void k_temporal(
    const float* __restrict__ X, const float* __restrict__ c1b,
    const float* __restrict__ c2b,
    const ushort_t* __restrict__ C1h, const ushort_t* __restrict__ C1l,
    const ushort_t* __restrict__ BmatT, float* __restrict__ Xf) {
  __shared__ __align__(16) unsigned char smem[SMEM_T];
  ushort_t* xph = (ushort_t*)(smem + OFF_XPH);   // [4][480]
  ushort_t* xpl = (ushort_t*)(smem + OFF_XPL);   // [4][480]
  ushort_t* p1T = (ushort_t*)(smem + OFF_P1);    // [4*40][40]
  float* Dbuf = (float*)smem;                    // overlay [64][66]

  const int tid = threadIdx.x;
  const int row0 = blockIdx.x * RPB;
  const int lane = tid & 63, wv = tid >> 6;
  const int quad = lane >> 4, nl = lane & 15;

  for (int i = tid; i < 3200; i += 256) ((unsigned*)p1T)[i] = 0u;
  for (int r = 0; r < RPB; ++r) {
    const int gr = row0 + r;
    const int n = gr % N_;
    const int s = (gr / N_) % SEG_;
    const int b = gr / (N_ * SEG_);
    const float* xin = X + (((size_t)b * N_ + n) * SEG_ + s) * T_ - 12;
    for (int i = tid; i < 480; i += 256) {
      float v = (i >= 12 && i < 412) ? xin[i] : 0.f;
      ushort_t h = f2bf(v);
      xph[r * 480 + i] = h;
      xpl[r * 480 + i] = f2bf(v - bf2f(h));
    }
  }
  __syncthreads();

  // ---- conv1 via MFMA (hi/lo x3) + bias + relu + pool4 -> p1T ----
  {
    bf16x8 bh0 = *(const bf16x8*)(C1h + nl * 32 + quad * 8);
    bf16x8 bh1 = *(const bf16x8*)(C1h + (16 + nl) * 32 + quad * 8);
    bf16x8 bl0 = *(const bf16x8*)(C1l + nl * 32 + quad * 8);
    bf16x8 bl1 = *(const bf16x8*)(C1l + (16 + nl) * 32 + quad * 8);
    const float bias0 = c1b[nl], bias1 = c1b[16 + nl];
    for (int t = wv; t < 28; t += 4) {
      const int r = t / 7, mt = t - r * 7;
      const int aoff = r * 480 + mt * 64 + nl * 4 + quad * 8;
      union { bf16x4 q[2]; bf16x8 v; } ah, al;
      ah.q[0] = *(const bf16x4*)(xph + aoff);
      ah.q[1] = *(const bf16x4*)(xph + aoff + 4);
      al.q[0] = *(const bf16x4*)(xpl + aoff);
      al.q[1] = *(const bf16x4*)(xpl + aoff + 4);
      f32x4 a0 = (f32x4){0.f, 0.f, 0.f, 0.f};
      a0 = __builtin_amdgcn_mfma_f32_16x16x32_bf16(ah.v, bh0, a0, 0, 0, 0);
      a0 = __builtin_amdgcn_mfma_f32_16x16x32_bf16(al.v, bh0, a0, 0, 0, 0);
      a0 = __builtin_amdgcn_mfma_f32_16x16x32_bf16(ah.v, bl0, a0, 0, 0, 0);
      f32x4 a1 = (f32x4){0.f, 0.f, 0.f, 0.f};
      a1 = __builtin_amdgcn_mfma_f32_16x16x32_bf16(ah.v, bh1, a1, 0, 0, 0);
      a1 = __builtin_amdgcn_mfma_f32_16x16x32_bf16(al.v, bh1, a1, 0, 0, 0);
      a1 = __builtin_amdgcn_mfma_f32_16x16x32_bf16(ah.v, bl1, a1, 0, 0, 0);
      const int j = mt * 4 + quad;     // pooled output index (pos/4)
      if (j < 25) {
        float m0 = fmaxf(fmaxf(a0[0], a0[1]), fmaxf(a0[2], a0[3]));
        float m1 = fmaxf(fmaxf(a1[0], a1[1]), fmaxf(a1[2], a1[3]));
        p1T[(r * P1R + j + 4) * ICP + nl] = f2bf(fmaxf(m0 + bias0, 0.f));
        p1T[(r * P1R + j + 4) * ICP + 16 + nl] = f2bf(fmaxf(m1 + bias1, 0.f));
      }
    }
  }
  __syncthreads();

  // ---- conv2 via MFMA ----
  f32x4 acc[4];
  int abase[4];
#pragma unroll
  for (int tm = 0; tm < 4; ++tm) {
    acc[tm] = (f32x4){0.f, 0.f, 0.f, 0.f};
    int m = tm * 16 + nl;
    int rl = m / 14;
    int op = m - rl * 14;
    if (rl > 3) rl = 3;
    if (op > 13) op = 13;
    abase[tm] = (rl * P1R + 2 * op) * ICP + quad * 8;
  }
  const ushort_t* brow = BmatT + (wv * 16 + nl) * 296 + quad * 8;
#pragma unroll
  for (int kk = 0; kk < 9; ++kk) {
    bf16x8 bfr = *(const bf16x8*)(brow + kk * 32);
#pragma unroll
    for (int tm = 0; tm < 4; ++tm) {
      bf16x8 afr = *(const bf16x8*)(p1T + abase[tm] + kk * ICP);
      acc[tm] = __builtin_amdgcn_mfma_f32_16x16x32_bf16(afr, bfr, acc[tm], 0, 0, 0);
    }
  }
  __syncthreads();   // xp/p1T dead -> Dbuf overlay safe

#pragma unroll
  for (int tm = 0; tm < 4; ++tm)
#pragma unroll
    for (int rg = 0; rg < 4; ++rg)
      Dbuf[(tm * 16 + quad * 4 + rg) * 66 + wv * 16 + nl] = acc[tm][rg];
  __syncthreads();

  for (int o = tid; o < RPB * 64; o += 256) {
    int rl = o >> 6, oc = o & 63;
    float bias = c2b[oc];
    const float* dr = Dbuf + (rl * 14) * 66 + oc;
    float s = 0.f;
#pragma unroll
    for (int jj = 0; jj < 6; ++jj) {
      float v = fmaxf(dr[(2 * jj) * 66], dr[(2 * jj + 1) * 66]) + bias;
      s += fmaxf(v, 0.f);
    }
    Xf[(size_t)(row0 + rl) * FIN_ + oc] = s * (1.f / 6.f);
  }
}

// ================= Kernel 2: fused GCN (unchanged) =================
__global__ __launch_bounds__(256) void k_gcn(
    const float* __restrict__ A, const float* __restrict__ Xf,
    const ushort_t* __restrict__ W1h, const ushort_t* __restrict__ W1l,
    const ushort_t* __restrict__ W2h, const ushort_t* __restrict__ W2l,
    const float* __restrict__ q1, const float* __restrict__ q2,
    const float* __restrict__ b1g, const float* __restrict__ b1b,
    const float* __restrict__ b1m, const float* __restrict__ b1v,
    const float* __restrict__ b2g, const float* __restrict__ b2b,
    const float* __restrict__ b2m, const float* __restrict__ b2v,
    float* __restrict__ G) {
  const int bs = blockIdx.x;
  const int b = bs / SEG_;
  const int s = bs % SEG_;
  const int tid = threadIdx.x;

  __shared__ __align__(16) ushort_t xh[32 * 72], xl[32 * 72];
  __shared__ __align__(16) ushort_t Hh[32 * 136], Hl[32 * 136];
  __shared__ float abar1[N_ * N_], abar2[N_ * N_];
  __shared__ float ybuf[N_ * 130];
  __shared__ float zbuf[N_ * 64];
  __shared__ float sc1[HID_], sh1[HID_], sc2[FIN_], sh2[FIN_];

  {
    float p0 = q1[0], p1 = q1[1], p2 = q1[2], p3 = q1[3];
    float mx = fmaxf(fmaxf(p0, p1), fmaxf(p2, p3));
    float e0 = expf(p0 - mx), e1 = expf(p1 - mx), e2 = expf(p2 - mx), e3 = expf(p3 - mx);
    float inv = 1.f / (e0 + e1 + e2 + e3);
    float a0 = e0 * inv, a1 = e1 * inv, a2 = e2 * inv, a3 = e3 * inv;
    float r0 = q2[0], r1 = q2[1], r2 = q2[2], r3 = q2[3];
    float mx2 = fmaxf(fmaxf(r0, r1), fmaxf(r2, r3));
    float f0 = expf(r0 - mx2), f1 = expf(r1 - mx2), f2 = expf(r2 - mx2), f3 = expf(r3 - mx2);
    float inv2 = 1.f / (f0 + f1 + f2 + f3);
    float c0 = f0 * inv2, c1 = f1 * inv2, c2 = f2 * inv2, c3 = f3 * inv2;
    const size_t kstride = (size_t)SEG_ * N_ * N_;
    const float* Ab = A + ((size_t)b * K_ * SEG_ + s) * (N_ * N_);
    for (int i = tid; i < N_ * N_; i += 256) {
      float v0 = Ab[i], v1 = Ab[i + kstride], v2 = Ab[i + 2 * kstride], v3 = Ab[i + 3 * kstride];
      abar1[i] = a0 * v0 + a1 * v1 + a2 * v2 + a3 * v3;
      abar2[i] = c0 * v0 + c1 * v1 + c2 * v2 + c3 * v3;
    }
  }

  for (int i = tid; i < 32 * 72 / 2; i += 256) {
    ((unsigned*)xh)[i] = 0u; ((unsigned*)xl)[i] = 0u;
  }
  for (int i = tid; i < 32 * 136 / 2; i += 256) {
    ((unsigned*)Hh)[i] = 0u; ((unsigned*)Hl)[i] = 0u;
  }
  for (int o = tid; o < HID_; o += 256) {
    float sc = b1g[o] * rsqrtf(b1v[o] + EPS_);
    sc1[o] = sc; sh1[o] = b1b[o] - b1m[o] * sc;
  }
  for (int o = tid; o < FIN_; o += 256) {
    float sc = b2g[o] * rsqrtf(b2v[o] + EPS_);
    sc2[o] = sc; sh2[o] = b2b[o] - b2m[o] * sc;
  }
  __syncthreads();

  const float* xb = Xf + (size_t)bs * N_ * FIN_;
  for (int i = tid; i < N_ * FIN_; i += 256) {
    int r = i >> 6, f = i & 63;
    float v = xb[i];
    ushort_t h = f2bf(v);
    xh[r * 72 + f] = h;
    xl[r * 72 + f] = f2bf(v - bf2f(h));
  }
  __syncthreads();

  const int lane = tid & 63, wv = tid >> 6;
  const int quad = lane >> 4, nl = lane & 15;

#pragma unroll
  for (int mt = 0; mt < 2; ++mt) {
#pragma unroll
    for (int ntl = 0; ntl < 2; ++ntl) {
      const int nt = wv * 2 + ntl;
      f32x4 acc = (f32x4){0.f, 0.f, 0.f, 0.f};
#pragma unroll
      for (int ks = 0; ks < 2; ++ks) {
        bf16x8 ah = *(const bf16x8*)(xh + (mt * 16 + nl) * 72 + ks * 32 + quad * 8);
        bf16x8 al = *(const bf16x8*)(xl + (mt * 16 + nl) * 72 + ks * 32 + quad * 8);
        bf16x8 bh = *(const bf16x8*)(W1h + (nt * 16 + nl) * 64 + ks * 32 + quad * 8);
        bf16x8 bl = *(const bf16x8*)(W1l + (nt * 16 + nl) * 64 + ks * 32 + quad * 8);
        acc = __builtin_amdgcn_mfma_f32_16x16x32_bf16(ah, bh, acc, 0, 0, 0);
        acc = __builtin_amdgcn_mfma_f32_16x16x32_bf16(al, bh, acc, 0, 0, 0);
        acc = __builtin_amdgcn_mfma_f32_16x16x32_bf16(ah, bl, acc, 0, 0, 0);
      }
#pragma unroll
      for (int r = 0; r < 4; ++r) {
        int m = mt * 16 + quad * 4 + r;
        if (m < N_) ybuf[m * 130 + nt * 16 + nl] = acc[r];
      }
    }
  }
  __syncthreads();

  for (int idx = tid; idx < N_ * HID_; idx += 256) {
    int nn = idx >> 7, o = idx & 127;
    float acc = 0.f;
    const float* ar = &abar1[nn * N_];
#pragma unroll
    for (int m = 0; m < N_; ++m) acc += ar[m] * ybuf[m * 130 + o];
    float h = fmaxf(acc * sc1[o] + sh1[o], 0.f);
    ushort_t hh = f2bf(h);
    Hh[nn * 136 + o] = hh;
    Hl[nn * 136 + o] = f2bf(h - bf2f(hh));
  }
  __syncthreads();

  {
    const int nt = wv;
#pragma unroll
    for (int mt = 0; mt < 2; ++mt) {
      f32x4 acc = (f32x4){0.f, 0.f, 0.f, 0.f};
#pragma unroll
      for (int ks = 0; ks < 4; ++ks) {
        bf16x8 ah = *(const bf16x8*)(Hh + (mt * 16 + nl) * 136 + ks * 32 + quad * 8);
        bf16x8 al = *(const bf16x8*)(Hl + (mt * 16 + nl) * 136 + ks * 32 + quad * 8);
        bf16x8 bh = *(const bf16x8*)(W2h + (nt * 16 + nl) * 128 + ks * 32 + quad * 8);
        bf16x8 bl = *(const bf16x8*)(W2l + (nt * 16 + nl) * 128 + ks * 32 + quad * 8);
        acc = __builtin_amdgcn_mfma_f32_16x16x32_bf16(ah, bh, acc, 0, 0, 0);
        acc = __builtin_amdgcn_mfma_f32_16x16x32_bf16(al, bh, acc, 0, 0, 0);
        acc = __builtin_amdgcn_mfma_f32_16x16x32_bf16(ah, bl, acc, 0, 0, 0);
      }
#pragma unroll
      for (int r = 0; r < 4; ++r) {
        int m = mt * 16 + quad * 4 + r;
        if (m < N_) ybuf[m * 66 + nt * 16 + nl] = acc[r];
      }
    }
  }
  __syncthreads();

  for (int idx = tid; idx < N_ * FIN_; idx += 256) {
    int nn = idx >> 6, o = idx & 63;
    float acc = 0.f;
    const float* ar = &abar2[nn * N_];
#pragma unroll
    for (int m = 0; m < N_; ++m) acc += ar[m] * ybuf[m * 66 + o];
    zbuf[idx] = fmaxf(acc * sc2[o] + sh2[o], 0.f);
  }
  __syncthreads();

  if (tid < FIN_) {
    float ssum = 0.f;
#pragma unroll
    for (int nn = 0; nn < N_; ++nn) ssum += zbuf[nn * 64 + tid];
    G[(size_t)bs * FIN_ + tid] = ssum * (1.f / (float)N_);
  }
}

// ================= Kernel 3: transformer (MFMA) + classifier =============
// Attention: one wave per head, no internal barriers (intra-wave LDS
// ordering). Weight GEMMs bf16x3 MFMA from L2.
__global__ __launch_bounds__(256) void k_transformer(
    const float* __restrict__ G, const float* __restrict__ cls,
    const float* __restrict__ pos,
    const ushort_t* __restrict__ Th, const ushort_t* __restrict__ Tl,
    const float* __restrict__ bqkv, const float* __restrict__ bo,
    const float* __restrict__ ln1g, const float* __restrict__ ln1b,
    const float* __restrict__ b1, const float* __restrict__ b2,
    const float* __restrict__ ln2g, const float* __restrict__ ln2b,
    const float* __restrict__ clfw, const float* __restrict__ clfb,
    float* __restrict__ out) {
  const int b = blockIdx.x;
  const int tid = threadIdx.x;
  const int lane = tid & 63, wv = tid >> 6;
  const int quad = lane >> 4, nl = lane & 15;

  __shared__ float xbuf[16 * 64];
  __shared__ __align__(16) ushort_t xh[16 * 72], xl[16 * 72];
  __shared__ float qkvb[16 * 196];
  __shared__ float scb[NH_ * 272];          // [h][t*17 + u]
  __shared__ __align__(16) ushort_t oh[16 * 72], ol[16 * 72];
  __shared__ __align__(16) ushort_t h1h[16 * 136], h1l[16 * 136];
  __shared__ float tmpb[16 * 64];

  for (int i = tid; i < 16 * 64; i += 256) {
    int t = i >> 6, d = i & 63;
    float base = (t == 0) ? cls[d] : G[((size_t)b * SEG_ + (t - 1)) * DM_ + d];
    float v = base + pos[t * DM_ + d];
    xbuf[i] = v;
    ushort_t h = f2bf(v);
    xh[t * 72 + d] = h;
    xl[t * 72 + d] = f2bf(v - bf2f(h));
  }
  __syncthreads();

  for (int l = 0; l < L_; ++l) {
    const ushort_t* TH = Th + l * 32768;
    const ushort_t* TL = Tl + l * 32768;

    // ---- qkv ----
#pragma unroll
    for (int ntl = 0; ntl < 3; ++ntl) {
      const int nt = wv * 3 + ntl;
      f32x4 acc = (f32x4){0.f, 0.f, 0.f, 0.f};
#pragma unroll
      for (int ks = 0; ks < 2; ++ks) {
        bf16x8 ah = *(const bf16x8*)(xh + nl * 72 + ks * 32 + quad * 8);
        bf16x8 al = *(const bf16x8*)(xl + nl * 72 + ks * 32 + quad * 8);
        bf16x8 bh = *(const bf16x8*)(TH + (nt * 16 + nl) * 64 + ks * 32 + quad * 8);
        bf16x8 bl = *(const bf16x8*)(TL + (nt * 16 + nl) * 64 + ks * 32 + quad * 8);
        acc = __builtin_amdgcn_mfma_f32_16x16x32_bf16(ah, bh, acc, 0, 0, 0);
        acc = __builtin_amdgcn_mfma_f32_16x16x32_bf16(al, bh, acc, 0, 0, 0);
        acc = __builtin_amdgcn_mfma_f32_16x16x32_bf16(ah, bl, acc, 0, 0, 0);
      }
      const int j = nt * 16 + nl;
      const float bias = bqkv[l * 192 + j];
#pragma unroll
      for (int r = 0; r < 4; ++r)
        qkvb[(quad * 4 + r) * 196 + j] = acc[r] + bias;
    }
    __syncthreads();

    // ---- attention: wave wv owns head wv; no internal barriers ----
    {
      const int h = wv;
      // scores: lane = (t=nl, u in quad*4..quad*4+3)
      float sc[4];
      const float* qr = &qkvb[nl * 196 + h * 16];
#pragma unroll
      for (int uu = 0; uu < 4; ++uu) {
        const float* kr = &qkvb[(quad * 4 + uu) * 196 + 64 + h * 16];
        float a = 0.f;
#pragma unroll
        for (int d = 0; d < 16; ++d) a += qr[d] * kr[d];
        sc[uu] = a * 0.25f;
      }
      // softmax over row t=nl (partners: lanes nl+16q)
      float mx = fmaxf(fmaxf(sc[0], sc[1]), fmaxf(sc[2], sc[3]));
      mx = fmaxf(mx, __shfl_xor(mx, 16));
      mx = fmaxf(mx, __shfl_xor(mx, 32));
      float e[4];
      float sum = 0.f;
#pragma unroll
      for (int uu = 0; uu < 4; ++uu) { e[uu] = expf(sc[uu] - mx); sum += e[uu]; }
      sum += __shfl_xor(sum, 16);
      sum += __shfl_xor(sum, 32);
      const float is = 1.f / sum;
      float* prow = &scb[h * 272 + nl * 17];
#pragma unroll
      for (int uu = 0; uu < 4; ++uu) prow[quad * 4 + uu] = e[uu] * is;
      // AV: lane = (t=nl, d in quad*4..quad*4+3); same-wave LDS, no barrier
      float o[4] = {0.f, 0.f, 0.f, 0.f};
      for (int u = 0; u < 16; ++u) {
        float p = prow[u];
        const float* vr = &qkvb[u * 196 + 128 + h * 16 + quad * 4];
#pragma unroll
        for (int dd = 0; dd < 4; ++dd) o[dd] += p * vr[dd];
      }
      const int eb = h * 16 + quad * 4;
#pragma unroll
      for (int dd = 0; dd < 4; ++dd) {
        ushort_t hh = f2bf(o[dd]);
        oh[nl * 72 + eb + dd] = hh;
        ol[nl * 72 + eb + dd] = f2bf(o[dd] - bf2f(hh));
      }
    }
    __syncthreads();

    // ---- proj + residual ----
    {
      const int nt = wv;
      f32x4 acc = (f32x4){0.f, 0.f, 0.f, 0.f};
#pragma unroll
      for (int ks = 0; ks < 2; ++ks) {
        bf16x8 ah = *(const bf16x8*)(oh + nl * 72 + ks * 32 + quad * 8);
        bf16x8 al = *(const bf16x8*)(ol + nl * 72 + ks * 32 + quad * 8);
        bf16x8 bh = *(const bf16x8*)(TH + 12288 + (nt * 16 + nl) * 64 + ks * 32 + quad * 8);
        bf16x8 bl = *(const bf16x8*)(TL + 12288 + (nt * 16 + nl) * 64 + ks * 32 + quad * 8);
        acc = __builtin_amdgcn_mfma_f32_16x16x32_bf16(ah, bh, acc, 0, 0, 0);
        acc = __builtin_amdgcn_mfma_f32_16x16x32_bf16(al, bh, acc, 0, 0, 0);
        acc = __builtin_amdgcn_mfma_f32_16x16x32_bf16(ah, bl, acc, 0, 0, 0);
      }
      const int d = nt * 16 + nl;
      const float bias = bo[l * 64 + d];
#pragma unroll
      for (int r = 0; r < 4; ++r) {
        int t = quad * 4 + r;
        tmpb[t * 64 + d] = xbuf[t * 64 + d] + acc[r] + bias;
      }
    }
    __syncthreads();

    // ---- LN1 ----
    {
      int t = tid >> 4, i2 = tid & 15;
      float4 v = ((const float4*)(tmpb + t * 64))[i2];
      float s = v.x + v.y + v.z + v.w;
      s += __shfl_xor(s, 1); s += __shfl_xor(s, 2);
      s += __shfl_xor(s, 4); s += __shfl_xor(s, 8);
      float mu = s * (1.f / 64.f);
      float d0 = v.x - mu, d1 = v.y - mu, d2 = v.z - mu, d3 = v.w - mu;
      float vr = d0 * d0 + d1 * d1 + d2 * d2 + d3 * d3;
      vr += __shfl_xor(vr, 1); vr += __shfl_xor(vr, 2);
      vr += __shfl_xor(vr, 4); vr += __shfl_xor(vr, 8);
      float rs = rsqrtf(vr * (1.f / 64.f) + EPS_);
      float4 g4 = ((const float4*)(ln1g + l * 64))[i2];
      float4 b4 = ((const float4*)(ln1b + l * 64))[i2];
      float4 o4;
      o4.x = d0 * rs * g4.x + b4.x; o4.y = d1 * rs * g4.y + b4.y;
      o4.z = d2 * rs * g4.z + b4.z; o4.w = d3 * rs * g4.w + b4.w;
      ((float4*)(xbuf + t * 64))[i2] = o4;
      int base = t * 72 + i2 * 4;
      ushort_t h0 = f2bf(o4.x), h1 = f2bf(o4.y), h2 = f2bf(o4.z), h3 = f2bf(o4.w);
      xh[base + 0] = h0; xh[base + 1] = h1; xh[base + 2] = h2; xh[base + 3] = h3;
      xl[base + 0] = f2bf(o4.x - bf2f(h0));
      xl[base + 1] = f2bf(o4.y - bf2f(h1));
      xl[base + 2] = f2bf(o4.z - bf2f(h2));
      xl[base + 3] = f2bf(o4.w - bf2f(h3));
    }
    __syncthreads();

    // ---- ff1 ----
#pragma unroll
    for (int ntl = 0; ntl < 2; ++ntl) {
      const int nt = wv * 2 + ntl;
      f32x4 acc = (f32x4){0.f, 0.f, 0.f, 0.f};
#pragma unroll
      for (int ks = 0; ks < 2; ++ks) {
        bf16x8 ah = *(const bf16x8*)(xh + nl * 72 + ks * 32 + quad * 8);
        bf16x8 al = *(const bf16x8*)(xl + nl * 72 + ks * 32 + quad * 8);
        bf16x8 bh = *(const bf16x8*)(TH + 16384 + (nt * 16 + nl) * 64 + ks * 32 + quad * 8);
        bf16x8 bl = *(const bf16x8*)(TL + 16384 + (nt * 16 + nl) * 64 + ks * 32 + quad * 8);
        acc = __builtin_amdgcn_mfma_f32_16x16x32_bf16(ah, bh, acc, 0, 0, 0);
        acc = __builtin_amdgcn_mfma_f32_16x16x32_bf16(al, bh, acc, 0, 0, 0);
        acc = __builtin_amdgcn_mfma_f32_16x16x32_bf16(ah, bl, acc, 0, 0, 0);
      }
      const int f = nt * 16 + nl;
      const float bias = b1[l * 128 + f];
#pragma unroll
      for (int r = 0; r < 4; ++r) {
        int t = quad * 4 + r;
        float v = fmaxf(acc[r] + bias, 0.f);
        ushort_t hh = f2bf(v);
        h1h[t * 136 + f] = hh;
        h1l[t * 136 + f] = f2bf(v - bf2f(hh));
      }
    }
    __syncthreads();

    // ---- ff2 + residual ----
    {
      const int nt = wv;
      f32x4 acc = (f32x4){0.f, 0.f, 0.f, 0.f};
#pragma unroll
      for (int ks = 0; ks < 4; ++ks) {
        bf16x8 ah = *(const bf16x8*)(h1h + nl * 136 + ks * 32 + quad * 8);
        bf16x8 al = *(const bf16x8*)(h1l + nl * 136 + ks * 32 + quad * 8);
        bf16x8 bh = *(const bf16x8*)(TH + 24576 + (nt * 16 + nl) * 128 + ks * 32 + quad * 8);
        bf16x8 bl = *(const bf16x8*)(TL + 24576 + (nt * 16 + nl) * 128 + ks * 32 + quad * 8);
        acc = __builtin_amdgcn_mfma_f32_16x16x32_bf16(ah, bh, acc, 0, 0, 0);
        acc = __builtin_amdgcn_mfma_f32_16x16x32_bf16(al, bh, acc, 0, 0, 0);
        acc = __builtin_amdgcn_mfma_f32_16x16x32_bf16(ah, bl, acc, 0, 0, 0);
      }
      const int d = nt * 16 + nl;
      const float bias = b2[l * 64 + d];
#pragma unroll
      for (int r = 0; r < 4; ++r) {
        int t = quad * 4 + r;
        tmpb[t * 64 + d] = xbuf[t * 64 + d] + acc[r] + bias;
      }
    }
    __syncthreads();

    // ---- LN2 ----
    {
      int t = tid >> 4, i2 = tid & 15;
      float4 v = ((const float4*)(tmpb + t * 64))[i2];
      float s = v.x + v.y + v.z + v.w;
      s += __shfl_xor(s, 1); s += __shfl_xor(s, 2);
      s += __shfl_xor(s, 4); s += __shfl_xor(s, 8);
      float mu = s * (1.f / 64.f);
      float d0 = v.x - mu, d1 = v.y - mu, d2 = v.z - mu, d3 = v.w - mu;
      float vr = d0 * d0 + d1 * d1 + d2 * d2 + d3 * d3;
      vr += __shfl_xor(vr, 1); vr += __shfl_xor(vr, 2);
      vr += __shfl_xor(vr, 4); vr += __shfl_xor(vr, 8);
      float rs = rsqrtf(vr * (1.f / 64.f) + EPS_);
      float4 g4 = ((const float4*)(ln2g + l * 64))[i2];
      float4 b4 = ((const float4*)(ln2b + l * 64))[i2];
      float4 o4;
      o4.x = d0 * rs * g4.x + b4.x; o4.y = d1 * rs * g4.y + b4.y;
      o4.z = d2 * rs * g4.z + b4.z; o4.w = d3 * rs * g4.w + b4.w;
      ((float4*)(xbuf + t * 64))[i2] = o4;
      int base = t * 72 + i2 * 4;
      ushort_t h0 = f2bf(o4.x), h1 = f2bf(o4.y), h2 = f2bf(o4.z), h3 = f2bf(o4.w);
      xh[base + 0] = h0; xh[base + 1] = h1; xh[base + 2] = h2; xh[base + 3] = h3;
      xl[base + 0] = f2bf(o4.x - bf2f(h0));
      xl[base + 1] = f2bf(o4.y - bf2f(h1));
      xl[base + 2] = f2bf(o4.z - bf2f(h2));
      xl[base + 3] = f2bf(o4.w - bf2f(h3));
    }
    __syncthreads();
  }

  if (tid < NC_) {
    float acc = clfb[tid];
    const float* wr = &clfw[tid * DM_];
    for (int d = 0; d < DM_; ++d) acc += xbuf[d] * wr[d];
    out[b * NC_ + tid] = acc;
  }
}

extern "C" void kernel_launch(void* const* d_in, const int* in_sizes, int n_in,
                              void* d_out, int out_size, void* d_ws, size_t ws_size,
                              hipStream_t stream) {
  (void)in_sizes; (void)n_in; (void)out_size; (void)ws_size;
  const float* X    = (const float*)d_in[0];
  const float* A    = (const float*)d_in[1];
  const float* c1w  = (const float*)d_in[2];
  const float* c1b  = (const float*)d_in[3];
  const float* c2w  = (const float*)d_in[4];
  const float* c2b  = (const float*)d_in[5];
  const float* g1W  = (const float*)d_in[6];
  const float* g1q  = (const float*)d_in[7];
  const float* g1g  = (const float*)d_in[8];
  const float* g1b  = (const float*)d_in[9];
  const float* g1m  = (const float*)d_in[10];
  const float* g1v  = (const float*)d_in[11];
  const float* g2W  = (const float*)d_in[12];
  const float* g2q  = (const float*)d_in[13];
  const float* g2g  = (const float*)d_in[14];
  const float* g2b  = (const float*)d_in[15];
  const float* g2m  = (const float*)d_in[16];
  const float* g2v  = (const float*)d_in[17];
  const float* cls  = (const float*)d_in[18];
  const float* pos  = (const float*)d_in[19];
  const float* wqkv = (const float*)d_in[20];
  const float* bqkv = (const float*)d_in[21];
  const float* wo   = (const float*)d_in[22];
  const float* bo   = (const float*)d_in[23];
  const float* ln1g = (const float*)d_in[24];
  const float* ln1b = (const float*)d_in[25];
  const float* w1   = (const float*)d_in[26];
  const float* b1   = (const float*)d_in[27];
  const float* w2   = (const float*)d_in[28];
  const float* b2   = (const float*)d_in[29];
  const float* ln2g = (const float*)d_in[30];
  const float* ln2b = (const float*)d_in[31];
  const float* clfw = (const float*)d_in[32];
  const float* clfb = (const float*)d_in[33];
  float* out = (float*)d_out;

  // ---- workspace layout (bytes) ----
  char* wsb = (char*)d_ws;
  ushort_t* BmatT = (ushort_t*)(wsb + 0);                  //  37888
  ushort_t* Th  = (ushort_t*)(wsb + 37888);                // 262144
  ushort_t* Tl  = (ushort_t*)(wsb + 300032);               // 262144
  ushort_t* W1h = (ushort_t*)(wsb + 562176);               //  16384
  ushort_t* W1l = (ushort_t*)(wsb + 578560);               //  16384
  ushort_t* W2h = (ushort_t*)(wsb + 594944);               //  16384
  ushort_t* W2l = (ushort_t*)(wsb + 611328);               //  16384
  ushort_t* C1h = (ushort_t*)(wsb + 627712);               //   2048
  ushort_t* C1l = (ushort_t*)(wsb + 629760);               //   2048
  float* Xf   = (float*)(wsb + 631808);                    // 4669440
  float* G    = (float*)(wsb + 5301248);                   //  245760 -> ~5.55 MB

  k_prep<<<654, 256, 0, stream>>>(c1w, c2w, wqkv, wo, w1, w2, g1W, g2W,
                                  BmatT, Th, Tl, W1h, W1l, W2h, W2l, C1h, C1l);
  k_temporal<<<B_ * SEG_ * N_ / RPB, 256, 0, stream>>>(
      X, c1b, c2b, C1h, C1l, BmatT, Xf);
  k_gcn<<<B_ * SEG_, 256, 0, stream>>>(A, Xf, W1h, W1l, W2h, W2l,
                                       g1q, g2q, g1g, g1b, g1m, g1v,
                                       g2g, g2b, g2m, g2v, G);
  k_transformer<<<B_, 256, 0, stream>>>(G, cls, pos, Th, Tl,
                                        bqkv, bo, ln1g, ln1b, b1, b2, ln2g, ln2b,
                                        clfw, clfb, out);
}

// Round 6
// 216.278 us; speedup vs baseline: 3.5331x; 1.0355x over previous
//
#include <hip/hip_runtime.h>
#include <cmath>

#define B_ 64
#define N_ 19
#define SEG_ 15
#define T_ 400
#define FIN_ 64
#define HID_ 128
#define K_ 4
#define NH_ 4
#define DM_ 64
#define FF_ 128
#define L_ 4
#define NC_ 3
#define EPS_ 1e-5f

typedef __attribute__((ext_vector_type(8))) short bf16x8;
typedef __attribute__((ext_vector_type(4))) short bf16x4;
typedef __attribute__((ext_vector_type(4))) float f32x4;
typedef unsigned short ushort_t;

__device__ __forceinline__ ushort_t f2bf(float x) {
  union { float f; unsigned u; } a; a.f = x;
  unsigned r = a.u + 0x7fffu + ((a.u >> 16) & 1u);
  return (ushort_t)(r >> 16);
}
__device__ __forceinline__ float bf2f(ushort_t h) {
  union { unsigned u; float f; } a; a.u = ((unsigned)h) << 16;
  return a.f;
}

// ================= k_prep =================
__global__ __launch_bounds__(256) void k_prep(
    const float* __restrict__ c1w, const float* __restrict__ c2w,
    const float* __restrict__ wqkv, const float* __restrict__ wo,
    const float* __restrict__ w1, const float* __restrict__ w2,
    const float* __restrict__ g1W, const float* __restrict__ g2W,
    ushort_t* __restrict__ bt,
    ushort_t* __restrict__ Th, ushort_t* __restrict__ Tl,
    ushort_t* __restrict__ W1h, ushort_t* __restrict__ W1l,
    ushort_t* __restrict__ W2h, ushort_t* __restrict__ W2l,
    ushort_t* __restrict__ C1h, ushort_t* __restrict__ C1l) {
  int gid = blockIdx.x * 256 + threadIdx.x;
  if (gid < 18944) {                       // BmatT[oc][kk*32+ic] = c2w[oc][ic][kk]
    int oc = gid / 296, k = gid - oc * 296;
    int ic = k & 31, kk = k >> 5;
    ushort_t v = 0;
    if (kk < 9) v = f2bf(c2w[oc * 288 + ic * 9 + kk]);
    bt[gid] = v;
  } else if (gid < 68096) {                // wqkv: L x 192 x 64
    int i = gid - 18944;
    int l = i / 12288, r = i % 12288;
    float v = wqkv[i];
    ushort_t h = f2bf(v);
    int dst = l * 32768 + r;
    Th[dst] = h; Tl[dst] = f2bf(v - bf2f(h));
  } else if (gid < 84480) {                // wo: L x 64 x 64
    int i = gid - 68096;
    int l = i / 4096, r = i % 4096;
    float v = wo[i];
    ushort_t h = f2bf(v);
    int dst = l * 32768 + 12288 + r;
    Th[dst] = h; Tl[dst] = f2bf(v - bf2f(h));
  } else if (gid < 117248) {               // w1: L x 128 x 64
    int i = gid - 84480;
    int l = i / 8192, r = i % 8192;
    float v = w1[i];
    ushort_t h = f2bf(v);
    int dst = l * 32768 + 16384 + r;
    Th[dst] = h; Tl[dst] = f2bf(v - bf2f(h));
  } else if (gid < 150016) {               // w2: L x 64 x 128
    int i = gid - 117248;
    int l = i / 8192, r = i % 8192;
    float v = w2[i];
    ushort_t h = f2bf(v);
    int dst = l * 32768 + 24576 + r;
    Th[dst] = h; Tl[dst] = f2bf(v - bf2f(h));
  } else if (gid < 158208) {               // g1_W split hi/lo [128][64]
    int i = gid - 150016;
    float v = g1W[i];
    ushort_t h = f2bf(v);
    W1h[i] = h;
    W1l[i] = f2bf(v - bf2f(h));
  } else if (gid < 166400) {               // g2_W split hi/lo [64][128]
    int i = gid - 158208;
    float v = g2W[i];
    ushort_t h = f2bf(v);
    W2h[i] = h;
    W2l[i] = f2bf(v - bf2f(h));
  } else if (gid < 167424) {               // conv1 w padded [32 oc][32 k] hi/lo
    int i = gid - 166400;
    int oc = i >> 5, kk = i & 31;
    float v = (kk < 25) ? c1w[oc * 25 + kk] : 0.f;
    ushort_t h = f2bf(v);
    C1h[i] = h;
    C1l[i] = f2bf(v - bf2f(h));
  }
}

// ================= Kernel 1: temporal encoder (unchanged from R5) ==========
#define RPB 4
#define ICP 40
#define P1R 40
#define OFF_XPH 0
#define OFF_XPL 3840
#define OFF_P1  7680
#define SMEM_T  20480

__global__ __launch_bounds__(256, 4) void k_temporal(
    const float* __restrict__ X, const float* __restrict__ c1b,
    const float* __restrict__ c2b,
    const ushort_t* __restrict__ C1h, const ushort_t* __restrict__ C1l,
    const ushort_t* __restrict__ BmatT, float* __restrict__ Xf) {
  __shared__ __align__(16) unsigned char smem[SMEM_T];
  ushort_t* xph = (ushort_t*)(smem + OFF_XPH);   // [4][480]
  ushort_t* xpl = (ushort_t*)(smem + OFF_XPL);   // [4][480]
  ushort_t* p1T = (ushort_t*)(smem + OFF_P1);    // [4*40][40]
  float* Dbuf = (float*)smem;                    // overlay [64][66]

  const int tid = threadIdx.x;
  const int row0 = blockIdx.x * RPB;
  const int lane = tid & 63, wv = tid >> 6;
  const int quad = lane >> 4, nl = lane & 15;

  for (int i = tid; i < 3200; i += 256) ((unsigned*)p1T)[i] = 0u;
  for (int r = 0; r < RPB; ++r) {
    const int gr = row0 + r;
    const int n = gr % N_;
    const int s = (gr / N_) % SEG_;
    const int b = gr / (N_ * SEG_);
    const float* xin = X + (((size_t)b * N_ + n) * SEG_ + s) * T_ - 12;
    for (int i = tid; i < 480; i += 256) {
      float v = (i >= 12 && i < 412) ? xin[i] : 0.f;
      ushort_t h = f2bf(v);
      xph[r * 480 + i] = h;
      xpl[r * 480 + i] = f2bf(v - bf2f(h));
    }
  }
  __syncthreads();

  // ---- conv1 via MFMA (hi/lo x3) + bias + relu + pool4 -> p1T ----
  {
    bf16x8 bh0 = *(const bf16x8*)(C1h + nl * 32 + quad * 8);
    bf16x8 bh1 = *(const bf16x8*)(C1h + (16 + nl) * 32 + quad * 8);
    bf16x8 bl0 = *(const bf16x8*)(C1l + nl * 32 + quad * 8);
    bf16x8 bl1 = *(const bf16x8*)(C1l + (16 + nl) * 32 + quad * 8);
    const float bias0 = c1b[nl], bias1 = c1b[16 + nl];
    for (int t = wv; t < 28; t += 4) {
      const int r = t / 7, mt = t - r * 7;
      const int aoff = r * 480 + mt * 64 + nl * 4 + quad * 8;
      union { bf16x4 q[2]; bf16x8 v; } ah, al;
      ah.q[0] = *(const bf16x4*)(xph + aoff);
      ah.q[1] = *(const bf16x4*)(xph + aoff + 4);
      al.q[0] = *(const bf16x4*)(xpl + aoff);
      al.q[1] = *(const bf16x4*)(xpl + aoff + 4);
      f32x4 a0 = (f32x4){0.f, 0.f, 0.f, 0.f};
      a0 = __builtin_amdgcn_mfma_f32_16x16x32_bf16(ah.v, bh0, a0, 0, 0, 0);
      a0 = __builtin_amdgcn_mfma_f32_16x16x32_bf16(al.v, bh0, a0, 0, 0, 0);
      a0 = __builtin_amdgcn_mfma_f32_16x16x32_bf16(ah.v, bl0, a0, 0, 0, 0);
      f32x4 a1 = (f32x4){0.f, 0.f, 0.f, 0.f};
      a1 = __builtin_amdgcn_mfma_f32_16x16x32_bf16(ah.v, bh1, a1, 0, 0, 0);
      a1 = __builtin_amdgcn_mfma_f32_16x16x32_bf16(al.v, bh1, a1, 0, 0, 0);
      a1 = __builtin_amdgcn_mfma_f32_16x16x32_bf16(ah.v, bl1, a1, 0, 0, 0);
      const int j = mt * 4 + quad;
      if (j < 25) {
        float m0 = fmaxf(fmaxf(a0[0], a0[1]), fmaxf(a0[2], a0[3]));
        float m1 = fmaxf(fmaxf(a1[0], a1[1]), fmaxf(a1[2], a1[3]));
        p1T[(r * P1R + j + 4) * ICP + nl] = f2bf(fmaxf(m0 + bias0, 0.f));
        p1T[(r * P1R + j + 4) * ICP + 16 + nl] = f2bf(fmaxf(m1 + bias1, 0.f));
      }
    }
  }
  __syncthreads();

  // ---- conv2 via MFMA ----
  f32x4 acc[4];
  int abase[4];
#pragma unroll
  for (int tm = 0; tm < 4; ++tm) {
    acc[tm] = (f32x4){0.f, 0.f, 0.f, 0.f};
    int m = tm * 16 + nl;
    int rl = m / 14;
    int op = m - rl * 14;
    if (rl > 3) rl = 3;
    if (op > 13) op = 13;
    abase[tm] = (rl * P1R + 2 * op) * ICP + quad * 8;
  }
  const ushort_t* brow = BmatT + (wv * 16 + nl) * 296 + quad * 8;
#pragma unroll
  for (int kk = 0; kk < 9; ++kk) {
    bf16x8 bfr = *(const bf16x8*)(brow + kk * 32);
#pragma unroll
    for (int tm = 0; tm < 4; ++tm) {
      bf16x8 afr = *(const bf16x8*)(p1T + abase[tm] + kk * ICP);
      acc[tm] = __builtin_amdgcn_mfma_f32_16x16x32_bf16(afr, bfr, acc[tm], 0, 0, 0);
    }
  }
  __syncthreads();

#pragma unroll
  for (int tm = 0; tm < 4; ++tm)
#pragma unroll
    for (int rg = 0; rg < 4; ++rg)
      Dbuf[(tm * 16 + quad * 4 + rg) * 66 + wv * 16 + nl] = acc[tm][rg];
  __syncthreads();

  for (int o = tid; o < RPB * 64; o += 256) {
    int rl = o >> 6, oc = o & 63;
    float bias = c2b[oc];
    const float* dr = Dbuf + (rl * 14) * 66 + oc;
    float s = 0.f;
#pragma unroll
    for (int jj = 0; jj < 6; ++jj) {
      float v = fmaxf(dr[(2 * jj) * 66], dr[(2 * jj + 1) * 66]) + bias;
      s += fmaxf(v, 0.f);
    }
    Xf[(size_t)(row0 + rl) * FIN_ + oc] = s * (1.f / 6.f);
  }
}

// ================= Kernel 2: fused GCN (unchanged) =================
__global__ __launch_bounds__(256) void k_gcn(
    const float* __restrict__ A, const float* __restrict__ Xf,
    const ushort_t* __restrict__ W1h, const ushort_t* __restrict__ W1l,
    const ushort_t* __restrict__ W2h, const ushort_t* __restrict__ W2l,
    const float* __restrict__ q1, const float* __restrict__ q2,
    const float* __restrict__ b1g, const float* __restrict__ b1b,
    const float* __restrict__ b1m, const float* __restrict__ b1v,
    const float* __restrict__ b2g, const float* __restrict__ b2b,
    const float* __restrict__ b2m, const float* __restrict__ b2v,
    float* __restrict__ G) {
  const int bs = blockIdx.x;
  const int b = bs / SEG_;
  const int s = bs % SEG_;
  const int tid = threadIdx.x;

  __shared__ __align__(16) ushort_t xh[32 * 72], xl[32 * 72];
  __shared__ __align__(16) ushort_t Hh[32 * 136], Hl[32 * 136];
  __shared__ float abar1[N_ * N_], abar2[N_ * N_];
  __shared__ float ybuf[N_ * 130];
  __shared__ float zbuf[N_ * 64];
  __shared__ float sc1[HID_], sh1[HID_], sc2[FIN_], sh2[FIN_];

  {
    float p0 = q1[0], p1 = q1[1], p2 = q1[2], p3 = q1[3];
    float mx = fmaxf(fmaxf(p0, p1), fmaxf(p2, p3));
    float e0 = expf(p0 - mx), e1 = expf(p1 - mx), e2 = expf(p2 - mx), e3 = expf(p3 - mx);
    float inv = 1.f / (e0 + e1 + e2 + e3);
    float a0 = e0 * inv, a1 = e1 * inv, a2 = e2 * inv, a3 = e3 * inv;
    float r0 = q2[0], r1 = q2[1], r2 = q2[2], r3 = q2[3];
    float mx2 = fmaxf(fmaxf(r0, r1), fmaxf(r2, r3));
    float f0 = expf(r0 - mx2), f1 = expf(r1 - mx2), f2 = expf(r2 - mx2), f3 = expf(r3 - mx2);
    float inv2 = 1.f / (f0 + f1 + f2 + f3);
    float c0 = f0 * inv2, c1 = f1 * inv2, c2 = f2 * inv2, c3 = f3 * inv2;
    const size_t kstride = (size_t)SEG_ * N_ * N_;
    const float* Ab = A + ((size_t)b * K_ * SEG_ + s) * (N_ * N_);
    for (int i = tid; i < N_ * N_; i += 256) {
      float v0 = Ab[i], v1 = Ab[i + kstride], v2 = Ab[i + 2 * kstride], v3 = Ab[i + 3 * kstride];
      abar1[i] = a0 * v0 + a1 * v1 + a2 * v2 + a3 * v3;
      abar2[i] = c0 * v0 + c1 * v1 + c2 * v2 + c3 * v3;
    }
  }

  for (int i = tid; i < 32 * 72 / 2; i += 256) {
    ((unsigned*)xh)[i] = 0u; ((unsigned*)xl)[i] = 0u;
  }
  for (int i = tid; i < 32 * 136 / 2; i += 256) {
    ((unsigned*)Hh)[i] = 0u; ((unsigned*)Hl)[i] = 0u;
  }
  for (int o = tid; o < HID_; o += 256) {
    float sc = b1g[o] * rsqrtf(b1v[o] + EPS_);
    sc1[o] = sc; sh1[o] = b1b[o] - b1m[o] * sc;
  }
  for (int o = tid; o < FIN_; o += 256) {
    float sc = b2g[o] * rsqrtf(b2v[o] + EPS_);
    sc2[o] = sc; sh2[o] = b2b[o] - b2m[o] * sc;
  }
  __syncthreads();

  const float* xb = Xf + (size_t)bs * N_ * FIN_;
  for (int i = tid; i < N_ * FIN_; i += 256) {
    int r = i >> 6, f = i & 63;
    float v = xb[i];
    ushort_t h = f2bf(v);
    xh[r * 72 + f] = h;
    xl[r * 72 + f] = f2bf(v - bf2f(h));
  }
  __syncthreads();

  const int lane = tid & 63, wv = tid >> 6;
  const int quad = lane >> 4, nl = lane & 15;

#pragma unroll
  for (int mt = 0; mt < 2; ++mt) {
#pragma unroll
    for (int ntl = 0; ntl < 2; ++ntl) {
      const int nt = wv * 2 + ntl;
      f32x4 acc = (f32x4){0.f, 0.f, 0.f, 0.f};
#pragma unroll
      for (int ks = 0; ks < 2; ++ks) {
        bf16x8 ah = *(const bf16x8*)(xh + (mt * 16 + nl) * 72 + ks * 32 + quad * 8);
        bf16x8 al = *(const bf16x8*)(xl + (mt * 16 + nl) * 72 + ks * 32 + quad * 8);
        bf16x8 bh = *(const bf16x8*)(W1h + (nt * 16 + nl) * 64 + ks * 32 + quad * 8);
        bf16x8 bl = *(const bf16x8*)(W1l + (nt * 16 + nl) * 64 + ks * 32 + quad * 8);
        acc = __builtin_amdgcn_mfma_f32_16x16x32_bf16(ah, bh, acc, 0, 0, 0);
        acc = __builtin_amdgcn_mfma_f32_16x16x32_bf16(al, bh, acc, 0, 0, 0);
        acc = __builtin_amdgcn_mfma_f32_16x16x32_bf16(ah, bl, acc, 0, 0, 0);
      }
#pragma unroll
      for (int r = 0; r < 4; ++r) {
        int m = mt * 16 + quad * 4 + r;
        if (m < N_) ybuf[m * 130 + nt * 16 + nl] = acc[r];
      }
    }
  }
  __syncthreads();

  for (int idx = tid; idx < N_ * HID_; idx += 256) {
    int nn = idx >> 7, o = idx & 127;
    float acc = 0.f;
    const float* ar = &abar1[nn * N_];
#pragma unroll
    for (int m = 0; m < N_; ++m) acc += ar[m] * ybuf[m * 130 + o];
    float h = fmaxf(acc * sc1[o] + sh1[o], 0.f);
    ushort_t hh = f2bf(h);
    Hh[nn * 136 + o] = hh;
    Hl[nn * 136 + o] = f2bf(h - bf2f(hh));
  }
  __syncthreads();

  {
    const int nt = wv;
#pragma unroll
    for (int mt = 0; mt < 2; ++mt) {
      f32x4 acc = (f32x4){0.f, 0.f, 0.f, 0.f};
#pragma unroll
      for (int ks = 0; ks < 4; ++ks) {
        bf16x8 ah = *(const bf16x8*)(Hh + (mt * 16 + nl) * 136 + ks * 32 + quad * 8);
        bf16x8 al = *(const bf16x8*)(Hl + (mt * 16 + nl) * 136 + ks * 32 + quad * 8);
        bf16x8 bh = *(const bf16x8*)(W2h + (nt * 16 + nl) * 128 + ks * 32 + quad * 8);
        bf16x8 bl = *(const bf16x8*)(W2l + (nt * 16 + nl) * 128 + ks * 32 + quad * 8);
        acc = __builtin_amdgcn_mfma_f32_16x16x32_bf16(ah, bh, acc, 0, 0, 0);
        acc = __builtin_amdgcn_mfma_f32_16x16x32_bf16(al, bh, acc, 0, 0, 0);
        acc = __builtin_amdgcn_mfma_f32_16x16x32_bf16(ah, bl, acc, 0, 0, 0);
      }
#pragma unroll
      for (int r = 0; r < 4; ++r) {
        int m = mt * 16 + quad * 4 + r;
        if (m < N_) ybuf[m * 66 + nt * 16 + nl] = acc[r];
      }
    }
  }
  __syncthreads();

  for (int idx = tid; idx < N_ * FIN_; idx += 256) {
    int nn = idx >> 6, o = idx & 63;
    float acc = 0.f;
    const float* ar = &abar2[nn * N_];
#pragma unroll
    for (int m = 0; m < N_; ++m) acc += ar[m] * ybuf[m * 66 + o];
    zbuf[idx] = fmaxf(acc * sc2[o] + sh2[o], 0.f);
  }
  __syncthreads();

  if (tid < FIN_) {
    float ssum = 0.f;
#pragma unroll
    for (int nn = 0; nn < N_; ++nn) ssum += zbuf[nn * 64 + tid];
    G[(size_t)bs * FIN_ + tid] = ssum * (1.f / (float)N_);
  }
}

// ================= Kernel 3: transformer + classifier =============
// All per-layer weight B-fragments register-prefetched at layer start
// (32 independent b128 loads/wave) -> one latency exposure per layer
// instead of one per stage.
__global__ __launch_bounds__(256, 1) void k_transformer(
    const float* __restrict__ G, const float* __restrict__ cls,
    const float* __restrict__ pos,
    const ushort_t* __restrict__ Th, const ushort_t* __restrict__ Tl,
    const float* __restrict__ bqkv, const float* __restrict__ bo,
    const float* __restrict__ ln1g, const float* __restrict__ ln1b,
    const float* __restrict__ b1, const float* __restrict__ b2,
    const float* __restrict__ ln2g, const float* __restrict__ ln2b,
    const float* __restrict__ clfw, const float* __restrict__ clfb,
    float* __restrict__ out) {
  const int b = blockIdx.x;
  const int tid = threadIdx.x;
  const int lane = tid & 63, wv = tid >> 6;
  const int quad = lane >> 4, nl = lane & 15;

  __shared__ float xbuf[16 * 64];
  __shared__ __align__(16) ushort_t xh[16 * 72], xl[16 * 72];
  __shared__ float qkvb[16 * 196];
  __shared__ float scb[NH_ * 272];          // [h][t*17 + u]
  __shared__ __align__(16) ushort_t oh[16 * 72], ol[16 * 72];
  __shared__ __align__(16) ushort_t h1h[16 * 136], h1l[16 * 136];
  __shared__ float tmpb[16 * 64];

  for (int i = tid; i < 16 * 64; i += 256) {
    int t = i >> 6, d = i & 63;
    float base = (t == 0) ? cls[d] : G[((size_t)b * SEG_ + (t - 1)) * DM_ + d];
    float v = base + pos[t * DM_ + d];
    xbuf[i] = v;
    ushort_t h = f2bf(v);
    xh[t * 72 + d] = h;
    xl[t * 72 + d] = f2bf(v - bf2f(h));
  }
  __syncthreads();

  for (int l = 0; l < L_; ++l) {
    const ushort_t* TH = Th + l * 32768;
    const ushort_t* TL = Tl + l * 32768;

    // ---- register-prefetch ALL weight fragments for this layer ----
    bf16x8 qwh[3][2], qwl[3][2];
#pragma unroll
    for (int ntl = 0; ntl < 3; ++ntl)
#pragma unroll
      for (int ks = 0; ks < 2; ++ks) {
        const int nt = wv * 3 + ntl;
        qwh[ntl][ks] = *(const bf16x8*)(TH + (nt * 16 + nl) * 64 + ks * 32 + quad * 8);
        qwl[ntl][ks] = *(const bf16x8*)(TL + (nt * 16 + nl) * 64 + ks * 32 + quad * 8);
      }
    bf16x8 owh[2], owl[2];
#pragma unroll
    for (int ks = 0; ks < 2; ++ks) {
      owh[ks] = *(const bf16x8*)(TH + 12288 + (wv * 16 + nl) * 64 + ks * 32 + quad * 8);
      owl[ks] = *(const bf16x8*)(TL + 12288 + (wv * 16 + nl) * 64 + ks * 32 + quad * 8);
    }
    bf16x8 f1h[2][2], f1l[2][2];
#pragma unroll
    for (int ntl = 0; ntl < 2; ++ntl)
#pragma unroll
      for (int ks = 0; ks < 2; ++ks) {
        const int nt = wv * 2 + ntl;
        f1h[ntl][ks] = *(const bf16x8*)(TH + 16384 + (nt * 16 + nl) * 64 + ks * 32 + quad * 8);
        f1l[ntl][ks] = *(const bf16x8*)(TL + 16384 + (nt * 16 + nl) * 64 + ks * 32 + quad * 8);
      }
    bf16x8 f2h[4], f2l[4];
#pragma unroll
    for (int ks = 0; ks < 4; ++ks) {
      f2h[ks] = *(const bf16x8*)(TH + 24576 + (wv * 16 + nl) * 128 + ks * 32 + quad * 8);
      f2l[ks] = *(const bf16x8*)(TL + 24576 + (wv * 16 + nl) * 128 + ks * 32 + quad * 8);
    }

    // ---- qkv ----
#pragma unroll
    for (int ntl = 0; ntl < 3; ++ntl) {
      const int nt = wv * 3 + ntl;
      f32x4 acc = (f32x4){0.f, 0.f, 0.f, 0.f};
#pragma unroll
      for (int ks = 0; ks < 2; ++ks) {
        bf16x8 ah = *(const bf16x8*)(xh + nl * 72 + ks * 32 + quad * 8);
        bf16x8 al = *(const bf16x8*)(xl + nl * 72 + ks * 32 + quad * 8);
        acc = __builtin_amdgcn_mfma_f32_16x16x32_bf16(ah, qwh[ntl][ks], acc, 0, 0, 0);
        acc = __builtin_amdgcn_mfma_f32_16x16x32_bf16(al, qwh[ntl][ks], acc, 0, 0, 0);
        acc = __builtin_amdgcn_mfma_f32_16x16x32_bf16(ah, qwl[ntl][ks], acc, 0, 0, 0);
      }
      const int j = nt * 16 + nl;
      const float bias = bqkv[l * 192 + j];
#pragma unroll
      for (int r = 0; r < 4; ++r)
        qkvb[(quad * 4 + r) * 196 + j] = acc[r] + bias;
    }
    __syncthreads();

    // ---- attention: wave wv owns head wv; no internal barriers ----
    {
      const int h = wv;
      float sc[4];
      const float* qr = &qkvb[nl * 196 + h * 16];
#pragma unroll
      for (int uu = 0; uu < 4; ++uu) {
        const float* kr = &qkvb[(quad * 4 + uu) * 196 + 64 + h * 16];
        float a = 0.f;
#pragma unroll
        for (int d = 0; d < 16; ++d) a += qr[d] * kr[d];
        sc[uu] = a * 0.25f;
      }
      float mx = fmaxf(fmaxf(sc[0], sc[1]), fmaxf(sc[2], sc[3]));
      mx = fmaxf(mx, __shfl_xor(mx, 16));
      mx = fmaxf(mx, __shfl_xor(mx, 32));
      float e[4];
      float sum = 0.f;
#pragma unroll
      for (int uu = 0; uu < 4; ++uu) { e[uu] = expf(sc[uu] - mx); sum += e[uu]; }
      sum += __shfl_xor(sum, 16);
      sum += __shfl_xor(sum, 32);
      const float is = 1.f / sum;
      float* prow = &scb[h * 272 + nl * 17];
#pragma unroll
      for (int uu = 0; uu < 4; ++uu) prow[quad * 4 + uu] = e[uu] * is;
      float o[4] = {0.f, 0.f, 0.f, 0.f};
      for (int u = 0; u < 16; ++u) {
        float p = prow[u];
        const float* vr = &qkvb[u * 196 + 128 + h * 16 + quad * 4];
#pragma unroll
        for (int dd = 0; dd < 4; ++dd) o[dd] += p * vr[dd];
      }
      const int eb = h * 16 + quad * 4;
#pragma unroll
      for (int dd = 0; dd < 4; ++dd) {
        ushort_t hh = f2bf(o[dd]);
        oh[nl * 72 + eb + dd] = hh;
        ol[nl * 72 + eb + dd] = f2bf(o[dd] - bf2f(hh));
      }
    }
    __syncthreads();

    // ---- proj + residual ----
    {
      f32x4 acc = (f32x4){0.f, 0.f, 0.f, 0.f};
#pragma unroll
      for (int ks = 0; ks < 2; ++ks) {
        bf16x8 ah = *(const bf16x8*)(oh + nl * 72 + ks * 32 + quad * 8);
        bf16x8 al = *(const bf16x8*)(ol + nl * 72 + ks * 32 + quad * 8);
        acc = __builtin_amdgcn_mfma_f32_16x16x32_bf16(ah, owh[ks], acc, 0, 0, 0);
        acc = __builtin_amdgcn_mfma_f32_16x16x32_bf16(al, owh[ks], acc, 0, 0, 0);
        acc = __builtin_amdgcn_mfma_f32_16x16x32_bf16(ah, owl[ks], acc, 0, 0, 0);
      }
      const int d = wv * 16 + nl;
      const float bias = bo[l * 64 + d];
#pragma unroll
      for (int r = 0; r < 4; ++r) {
        int t = quad * 4 + r;
        tmpb[t * 64 + d] = xbuf[t * 64 + d] + acc[r] + bias;
      }
    }
    __syncthreads();

    // ---- LN1 ----
    {
      int t = tid >> 4, i2 = tid & 15;
      float4 v = ((const float4*)(tmpb + t * 64))[i2];
      float s = v.x + v.y + v.z + v.w;
      s += __shfl_xor(s, 1); s += __shfl_xor(s, 2);
      s += __shfl_xor(s, 4); s += __shfl_xor(s, 8);
      float mu = s * (1.f / 64.f);
      float d0 = v.x - mu, d1 = v.y - mu, d2 = v.z - mu, d3 = v.w - mu;
      float vr = d0 * d0 + d1 * d1 + d2 * d2 + d3 * d3;
      vr += __shfl_xor(vr, 1); vr += __shfl_xor(vr, 2);
      vr += __shfl_xor(vr, 4); vr += __shfl_xor(vr, 8);
      float rs = rsqrtf(vr * (1.f / 64.f) + EPS_);
      float4 g4 = ((const float4*)(ln1g + l * 64))[i2];
      float4 b4 = ((const float4*)(ln1b + l * 64))[i2];
      float4 o4;
      o4.x = d0 * rs * g4.x + b4.x; o4.y = d1 * rs * g4.y + b4.y;
      o4.z = d2 * rs * g4.z + b4.z; o4.w = d3 * rs * g4.w + b4.w;
      ((float4*)(xbuf + t * 64))[i2] = o4;
      int base = t * 72 + i2 * 4;
      ushort_t h0 = f2bf(o4.x), h1 = f2bf(o4.y), h2 = f2bf(o4.z), h3 = f2bf(o4.w);
      xh[base + 0] = h0; xh[base + 1] = h1; xh[base + 2] = h2; xh[base + 3] = h3;
      xl[base + 0] = f2bf(o4.x - bf2f(h0));
      xl[base + 1] = f2bf(o4.y - bf2f(h1));
      xl[base + 2] = f2bf(o4.z - bf2f(h2));
      xl[base + 3] = f2bf(o4.w - bf2f(h3));
    }
    __syncthreads();

    // ---- ff1 ----
#pragma unroll
    for (int ntl = 0; ntl < 2; ++ntl) {
      const int nt = wv * 2 + ntl;
      f32x4 acc = (f32x4){0.f, 0.f, 0.f, 0.f};
#pragma unroll
      for (int ks = 0; ks < 2; ++ks) {
        bf16x8 ah = *(const bf16x8*)(xh + nl * 72 + ks * 32 + quad * 8);
        bf16x8 al = *(const bf16x8*)(xl + nl * 72 + ks * 32 + quad * 8);
        acc = __builtin_amdgcn_mfma_f32_16x16x32_bf16(ah, f1h[ntl][ks], acc, 0, 0, 0);
        acc = __builtin_amdgcn_mfma_f32_16x16x32_bf16(al, f1h[ntl][ks], acc, 0, 0, 0);
        acc = __builtin_amdgcn_mfma_f32_16x16x32_bf16(ah, f1l[ntl][ks], acc, 0, 0, 0);
      }
      const int f = nt * 16 + nl;
      const float bias = b1[l * 128 + f];
#pragma unroll
      for (int r = 0; r < 4; ++r) {
        int t = quad * 4 + r;
        float v = fmaxf(acc[r] + bias, 0.f);
        ushort_t hh = f2bf(v);
        h1h[t * 136 + f] = hh;
        h1l[t * 136 + f] = f2bf(v - bf2f(hh));
      }
    }
    __syncthreads();

    // ---- ff2 + residual ----
    {
      f32x4 acc = (f32x4){0.f, 0.f, 0.f, 0.f};
#pragma unroll
      for (int ks = 0; ks < 4; ++ks) {
        bf16x8 ah = *(const bf16x8*)(h1h + nl * 136 + ks * 32 + quad * 8);
        bf16x8 al = *(const bf16x8*)(h1l + nl * 136 + ks * 32 + quad * 8);
        acc = __builtin_amdgcn_mfma_f32_16x16x32_bf16(ah, f2h[ks], acc, 0, 0, 0);
        acc = __builtin_amdgcn_mfma_f32_16x16x32_bf16(al, f2h[ks], acc, 0, 0, 0);
        acc = __builtin_amdgcn_mfma_f32_16x16x32_bf16(ah, f2l[ks], acc, 0, 0, 0);
      }
      const int d = wv * 16 + nl;
      const float bias = b2[l * 64 + d];
#pragma unroll
      for (int r = 0; r < 4; ++r) {
        int t = quad * 4 + r;
        tmpb[t * 64 + d] = xbuf[t * 64 + d] + acc[r] + bias;
      }
    }
    __syncthreads();

    // ---- LN2 ----
    {
      int t = tid >> 4, i2 = tid & 15;
      float4 v = ((const float4*)(tmpb + t * 64))[i2];
      float s = v.x + v.y + v.z + v.w;
      s += __shfl_xor(s, 1); s += __shfl_xor(s, 2);
      s += __shfl_xor(s, 4); s += __shfl_xor(s, 8);
      float mu = s * (1.f / 64.f);
      float d0 = v.x - mu, d1 = v.y - mu, d2 = v.z - mu, d3 = v.w - mu;
      float vr = d0 * d0 + d1 * d1 + d2 * d2 + d3 * d3;
      vr += __shfl_xor(vr, 1); vr += __shfl_xor(vr, 2);
      vr += __shfl_xor(vr, 4); vr += __shfl_xor(vr, 8);
      float rs = rsqrtf(vr * (1.f / 64.f) + EPS_);
      float4 g4 = ((const float4*)(ln2g + l * 64))[i2];
      float4 b4 = ((const float4*)(ln2b + l * 64))[i2];
      float4 o4;
      o4.x = d0 * rs * g4.x + b4.x; o4.y = d1 * rs * g4.y + b4.y;
      o4.z = d2 * rs * g4.z + b4.z; o4.w = d3 * rs * g4.w + b4.w;
      ((float4*)(xbuf + t * 64))[i2] = o4;
      int base = t * 72 + i2 * 4;
      ushort_t h0 = f2bf(o4.x), h1 = f2bf(o4.y), h2 = f2bf(o4.z), h3 = f2bf(o4.w);
      xh[base + 0] = h0; xh[base + 1] = h1; xh[base + 2] = h2; xh[base + 3] = h3;
      xl[base + 0] = f2bf(o4.x - bf2f(h0));
      xl[base + 1] = f2bf(o4.y - bf2f(h1));
      xl[base + 2] = f2bf(o4.z - bf2f(h2));
      xl[base + 3] = f2bf(o4.w - bf2f(h3));
    }
    __syncthreads();
  }

  if (tid < NC_) {
    float acc = clfb[tid];
    const float* wr = &clfw[tid * DM_];
    for (int d = 0; d < DM_; ++d) acc += xbuf[d] * wr[d];
    out[b * NC_ + tid] = acc;
  }
}

extern "C" void kernel_launch(void* const* d_in, const int* in_sizes, int n_in,
                              void* d_out, int out_size, void* d_ws, size_t ws_size,
                              hipStream_t stream) {
  (void)in_sizes; (void)n_in; (void)out_size; (void)ws_size;
  const float* X    = (const float*)d_in[0];
  const float* A    = (const float*)d_in[1];
  const float* c1w  = (const float*)d_in[2];
  const float* c1b  = (const float*)d_in[3];
  const float* c2w  = (const float*)d_in[4];
  const float* c2b  = (const float*)d_in[5];
  const float* g1W  = (const float*)d_in[6];
  const float* g1q  = (const float*)d_in[7];
  const float* g1g  = (const float*)d_in[8];
  const float* g1b  = (const float*)d_in[9];
  const float* g1m  = (const float*)d_in[10];
  const float* g1v  = (const float*)d_in[11];
  const float* g2W  = (const float*)d_in[12];
  const float* g2q  = (const float*)d_in[13];
  const float* g2g  = (const float*)d_in[14];
  const float* g2b  = (const float*)d_in[15];
  const float* g2m  = (const float*)d_in[16];
  const float* g2v  = (const float*)d_in[17];
  const float* cls  = (const float*)d_in[18];
  const float* pos  = (const float*)d_in[19];
  const float* wqkv = (const float*)d_in[20];
  const float* bqkv = (const float*)d_in[21];
  const float* wo   = (const float*)d_in[22];
  const float* bo   = (const float*)d_in[23];
  const float* ln1g = (const float*)d_in[24];
  const float* ln1b = (const float*)d_in[25];
  const float* w1   = (const float*)d_in[26];
  const float* b1   = (const float*)d_in[27];
  const float* w2   = (const float*)d_in[28];
  const float* b2   = (const float*)d_in[29];
  const float* ln2g = (const float*)d_in[30];
  const float* ln2b = (const float*)d_in[31];
  const float* clfw = (const float*)d_in[32];
  const float* clfb = (const float*)d_in[33];
  float* out = (float*)d_out;

  // ---- workspace layout (bytes) ----
  char* wsb = (char*)d_ws;
  ushort_t* BmatT = (ushort_t*)(wsb + 0);                  //  37888
  ushort_t* Th  = (ushort_t*)(wsb + 37888);                // 262144
  ushort_t* Tl  = (ushort_t*)(wsb + 300032);               // 262144
  ushort_t* W1h = (ushort_t*)(wsb + 562176);               //  16384
  ushort_t* W1l = (ushort_t*)(wsb + 578560);               //  16384
  ushort_t* W2h = (ushort_t*)(wsb + 594944);               //  16384
  ushort_t* W2l = (ushort_t*)(wsb + 611328);               //  16384
  ushort_t* C1h = (ushort_t*)(wsb + 627712);               //   2048
  ushort_t* C1l = (ushort_t*)(wsb + 629760);               //   2048
  float* Xf   = (float*)(wsb + 631808);                    // 4669440
  float* G    = (float*)(wsb + 5301248);                   //  245760 -> ~5.55 MB

  k_prep<<<654, 256, 0, stream>>>(c1w, c2w, wqkv, wo, w1, w2, g1W, g2W,
                                  BmatT, Th, Tl, W1h, W1l, W2h, W2l, C1h, C1l);
  k_temporal<<<B_ * SEG_ * N_ / RPB, 256, 0, stream>>>(
      X, c1b, c2b, C1h, C1l, BmatT, Xf);
  k_gcn<<<B_ * SEG_, 256, 0, stream>>>(A, Xf, W1h, W1l, W2h, W2l,
                                       g1q, g2q, g1g, g1b, g1m, g1v,
                                       g2g, g2b, g2m, g2v, G);
  k_transformer<<<B_, 256, 0, stream>>>(G, cls, pos, Th, Tl,
                                        bqkv, bo, ln1g, ln1b, b1, b2, ln2g, ln2b,
                                        clfw, clfb, out);
}